// Round 3
// baseline (747.066 us; speedup 1.0000x reference)
//
#include <hip/hip_runtime.h>
#include <math.h>

#define DD    128
#define TWOD  256
#define FOURD 512
#define NBN   30
#define BQ    4096
#define FEWN  5
#define NSYM  200000
#define KTOT  768    // 256 (query) + 256 (h) + 256 (r)
#define NGATE 1024   // 256 live units x 4 gates (units 256..511 are dead)
#define ULIVE 256
#define TOTU  (2 * BQ + 2 * FEWN)   // 8202 row-units
#define UPB   4                      // units per block (neighbor kernel)
#define GSZ   (NBN * DD)             // floats per staged group (30 rows x 128)

typedef short bf16x8 __attribute__((ext_vector_type(8)));
typedef float f32x4 __attribute__((ext_vector_type(4)));

__device__ __forceinline__ float sigmoidf_(float x) { return 1.0f / (1.0f + expf(-x)); }

// fast tanh: 1 - 2/(e^{2x}+1)  (v_exp + v_rcp; |err| ~1e-6, saturates correctly)
__device__ __forceinline__ float ftanh(float x) {
    float e = __expf(2.0f * x);
    return 1.0f - 2.0f / (e + 1.0f);
}

__device__ __forceinline__ unsigned short f2bf(float f) {
    unsigned int u = __float_as_uint(f);
    unsigned int r = (u + 0x7fffu + ((u >> 16) & 1u)) >> 16;
    return (unsigned short)r;
}

// pack 8 fp32 -> bf16x8 (round-to-nearest-ish)
__device__ __forceinline__ bf16x8 pack8(float4 a, float4 b) {
    union { bf16x8 v; unsigned int u[4]; } r;
    r.u[0] = ((__float_as_uint(a.x) + 0x8000u) >> 16) | ((__float_as_uint(a.y) + 0x8000u) & 0xffff0000u);
    r.u[1] = ((__float_as_uint(a.z) + 0x8000u) >> 16) | ((__float_as_uint(a.w) + 0x8000u) & 0xffff0000u);
    r.u[2] = ((__float_as_uint(b.x) + 0x8000u) >> 16) | ((__float_as_uint(b.y) + 0x8000u) & 0xffff0000u);
    r.u[3] = ((__float_as_uint(b.z) + 0x8000u) >> 16) | ((__float_as_uint(b.w) + 0x8000u) & 0xffff0000u);
    return r.v;
}

__device__ __forceinline__ void gload_lds16(const void* g, void* l) {
    __builtin_amdgcn_global_load_lds((const __attribute__((address_space(1))) unsigned int*)g,
                                     (__attribute__((address_space(3))) unsigned int*)l,
                                     16, 0, 0);
}

// ---------------- K0: one-time weight prep -------------------------------------
__global__ __launch_bounds__(256) void k_prep(
    const float* __restrict__ Wih, const float* __restrict__ Whh,
    const float* __restrict__ bih, const float* __restrict__ bhh,
    const float* __restrict__ p1W, const float* __restrict__ p2W,
    const float* __restrict__ nW, const float* __restrict__ nvW,
    unsigned short* __restrict__ Wbf, float* __restrict__ biasR,
    float* __restrict__ p1WT, float* __restrict__ p2WT,
    unsigned short* __restrict__ Nbf)
{
    int idx = blockIdx.x * 256 + threadIdx.x;
    int stride = gridDim.x * 256;
    for (int i = idx; i < NGATE * KTOT; i += stride) {
        int n = i / KTOT, k = i - n * KTOT;
        int blk = n >> 6, rem = n & 63;
        int g = rem >> 4, ul = rem & 15;
        int u = blk * 16 + ul;
        int srcrow = g * 512 + u;
        float v = (k < TWOD) ? Wih[srcrow * TWOD + k] : Whh[srcrow * FOURD + (k - TWOD)];
        Wbf[i] = f2bf(v);
    }
    for (int n = idx; n < NGATE; n += stride) {
        int blk = n >> 6, rem = n & 63;
        int g = rem >> 4, ul = rem & 15;
        int u = blk * 16 + ul;
        int srcrow = g * 512 + u;
        biasR[n] = bih[srcrow] + bhh[srcrow];
    }
    for (int i = idx; i < FOURD * TWOD; i += stride) {
        int o = i / TWOD, j = i % TWOD;
        p1WT[j * FOURD + o] = p1W[o * TWOD + j];
    }
    for (int i = idx; i < TWOD * FOURD; i += stride) {
        int o = i / FOURD, j = i % FOURD;
        p2WT[j * TWOD + o] = p2W[o * FOURD + j];
    }
    for (int i = idx; i < 2 * DD * TWOD; i += stride) {
        float v = (i < DD * TWOD) ? nW[i] : nvW[i - DD * TWOD];
        Nbf[i] = f2bf(v);
    }
}

// ---------------- K1 v7: neighbor encoder, path-split blocks for occupancy ------
// blockIdx.y = path (0: mean, 1: var). Each block stages only its path's two
// row-groups (rel_p, ent_p) as fp32 [30][128] via global_load_lds with
// source-swizzled 16B blocks (block ^ (row&7)); LDS ~35 KB, Bf per wave = 64
// VGPR (n-slice of 32 per wave) -> target 4 blocks/CU so inter-block TLP
// covers the per-unit gather drain at the post-stage barrier.
// Path 1 pools ent_e straight from global (emb is L2/L3-resident; coalesced
// 256B per neighbor) instead of staging a third group.
__global__ __launch_bounds__(256, 4) void k_neighbor_v7(
    const float* __restrict__ emb, const float* __restrict__ emb_var,
    const unsigned short* __restrict__ Nbf,
    const float* __restrict__ nWb, const float* __restrict__ nu,
    const float* __restrict__ nvWb, const float* __restrict__ nvu,
    const int* __restrict__ q_left, const int* __restrict__ q_right,
    const int* __restrict__ s_left, const int* __restrict__ s_right,
    float* __restrict__ query, float* __restrict__ support)
{
    const int tid  = threadIdx.x;
    const int wave = tid >> 6, lane = tid & 63;
    const int quad = lane >> 4, m15 = lane & 15;
    const int path = blockIdx.y;
    const int u0   = blockIdx.x * UPB;

    // 2 slots x 30x128 fp32 + 256 floats slack (rows 30/31 overread of slot 1)
    __shared__ __align__(16) float G[2 * GSZ + 2 * DD];
    __shared__ int   sidxL[UPB][64];
    __shared__ float aP[4][32];
    __shared__ float attL[32];
    __shared__ float poolP[2][DD];

    // ---- block init: neighbor indices for all UPB units (256 = UPB*64) ----
    {
        int un = tid >> 6, i = tid & 63;
        int uu_ = u0 + un; if (uu_ >= TOTU) uu_ = TOTU - 1;
        const int* conn;
        if (uu_ < BQ)                 conn = q_left  + uu_ * (NBN * 2);
        else if (uu_ < 2 * BQ)        conn = q_right + (uu_ - BQ) * (NBN * 2);
        else if (uu_ < 2 * BQ + FEWN) conn = s_left  + (uu_ - 2 * BQ) * (NBN * 2);
        else                          conn = s_right + (uu_ - 2 * BQ - FEWN) * (NBN * 2);
        sidxL[un][i] = (i < NBN * 2) ? conn[i] : NSYM;
    }

    // ---- per-wave constants: B fragments (64 VGPR), n-slice = wave*32 ----
    const unsigned short* Bw = Nbf + (size_t)path * DD * TWOD;
    const float* Wb  = path ? nvWb : nWb;
    const float* uu  = path ? nvu  : nu;
    const float* tbl = path ? emb_var : emb;
    bf16x8 Bf[2][8];
    float nb[2], un_[2];
#pragma unroll
    for (int t = 0; t < 2; ++t) {
        int n = wave * 32 + t * 16 + m15;
#pragma unroll
        for (int kt = 0; kt < 8; ++kt)
            Bf[t][kt] = *(const bf16x8*)(Bw + n * TWOD + kt * 32 + quad * 8);
        nb[t] = Wb[n];
        un_[t] = uu[n];
    }
    __syncthreads();                       // sidx visible (also drains Bf loads)

    for (int r = 0; r < UPB; ++r) {
        const int uidx = u0 + r;

        // ---- stage: slot = wave>>1 (0: rel/side0, 1: ent/side1) -----------
        {
            const int slot = wave >> 1, half = wave & 1;
            const int rl = lane >> 5, cb = lane & 31;
            float* base = G + slot * GSZ;
#pragma unroll
            for (int i = 0; i < 8; ++i) {
                const int pi = half * 8 + i;     // pair index: 2 rows / instr
                if (pi < 15) {
                    const int row = 2 * pi + rl;
                    const int sym = sidxL[r][2 * row + slot];
                    const float* src = tbl + (size_t)sym * DD + ((cb ^ (row & 7)) << 2);
                    gload_lds16(src, base + 2 * pi * DD);
                }
            }
        }
        __syncthreads();                   // S1: staging visible

        // ---- MFMA: S[32m x 32n per wave] = cat * W_p^T (fp32->bf16 on read) ----
        f32x4 acc[2][2] = {};
#pragma unroll
        for (int kt = 0; kt < 8; ++kt) {
            const float* sb = G + ((kt < 4) ? 0 : GSZ);
            const int cb0 = (kt & 3) * 8 + quad * 2;   // 16B-block of first half
            bf16x8 fa[2];
#pragma unroll
            for (int mt = 0; mt < 2; ++mt) {
                const int row = mt * 16 + m15;
                const float* rp = sb + row * DD;
                const int s = row & 7;
                float4 x0 = *(const float4*)(rp + ((cb0 ^ s) << 2));
                float4 x1 = *(const float4*)(rp + (((cb0 + 1) ^ s) << 2));
                fa[mt] = pack8(x0, x1);
            }
#pragma unroll
            for (int mt = 0; mt < 2; ++mt)
#pragma unroll
                for (int nt = 0; nt < 2; ++nt)
                    acc[mt][nt] = __builtin_amdgcn_mfma_f32_16x16x32_bf16(fa[mt], Bf[nt][kt], acc[mt][nt], 0, 0, 0);
        }

        // ---- epilogue: partial a[m] = sum_n u[n]*tanh(S+b) over 32-n slice ----
        {
            float part[2][4];
#pragma unroll
            for (int mt = 0; mt < 2; ++mt)
#pragma unroll
                for (int rr = 0; rr < 4; ++rr) {
                    float s = 0.f;
#pragma unroll
                    for (int nt = 0; nt < 2; ++nt)
                        s += un_[nt] * ftanh(acc[mt][nt][rr] + nb[nt]);
                    part[mt][rr] = s;
                }
#pragma unroll
            for (int off = 1; off < 16; off <<= 1)
#pragma unroll
                for (int mt = 0; mt < 2; ++mt)
#pragma unroll
                    for (int rr = 0; rr < 4; ++rr)
                        part[mt][rr] += __shfl_xor(part[mt][rr], off, 64);
            if (m15 == 0) {
#pragma unroll
                for (int mt = 0; mt < 2; ++mt)
#pragma unroll
                    for (int rr = 0; rr < 4; ++rr)
                        aP[wave][mt * 16 + quad * 4 + rr] = part[mt][rr];
            }
        }
        __syncthreads();                   // S2

        // ---- softmax over 30 neighbors (wave 0) ----
        if (wave == 0 && lane < 32) {
            float sc = (lane < NBN) ? aP[0][lane] + aP[1][lane] + aP[2][lane] + aP[3][lane]
                                    : -1e30f;
            float mx = sc;
#pragma unroll
            for (int off = 1; off < 32; off <<= 1) mx = fmaxf(mx, __shfl_xor(mx, off, 64));
            float e = (lane < NBN) ? __expf(sc - mx) : 0.f;
            float sum = e;
#pragma unroll
            for (int off = 1; off < 32; off <<= 1) sum += __shfl_xor(sum, off, 64);
            attL[lane] = e / sum;
        }
        __syncthreads();                   // S3

        // ---- pool ent_e partial: split-k across the two thread halves ----
        {
            const int half = tid >> 7, d = tid & 127;
            const int k0 = half * 15;
            float pp = 0.f;
            if (path == 0) {
                const float* g1p = G + GSZ;        // slot1 == ent_e for path 0
                const int cbp = d >> 2, ofs = d & 3;
#pragma unroll
                for (int k = k0; k < k0 + 15; ++k)
                    pp += attL[k] * g1p[k * DD + ((cbp ^ (k & 7)) << 2) + ofs];
            } else {
#pragma unroll
                for (int k = k0; k < k0 + 15; ++k) {
                    const int sym = sidxL[r][2 * k + 1];
                    pp += attL[k] * emb[(size_t)sym * DD + d];   // L2/L3-hot, coalesced
                }
            }
            poolP[half][d] = pp;
        }
        __syncthreads();                   // S4: poolP visible; G reads done

        if (tid < DD && uidx < TOTU) {
            const int d = tid;
            float pool = poolP[0][d] + poolP[1][d];
            float* dst;
            if (uidx < BQ)                 dst = query   + ((size_t)path * BQ + uidx) * TWOD;
            else if (uidx < 2 * BQ)        dst = query   + ((size_t)path * BQ + (uidx - BQ)) * TWOD + DD;
            else if (uidx < 2 * BQ + FEWN) dst = support + ((size_t)path * FEWN + (uidx - 2 * BQ)) * TWOD;
            else                           dst = support + ((size_t)path * FEWN + (uidx - 2 * BQ - FEWN)) * TWOD + DD;
            dst[d] = ftanh(pool);
        }
        // next stage2 (after loop top) writes G: all G reads completed before S4 ✓
    }
}

// ---------------- K2: support encoder (MLP + residual + layernorm ddof=1) ------
template <int RPB>
__global__ __launch_bounds__(256) void k_supenc(
    const float* __restrict__ xin, float* __restrict__ xout,
    unsigned short* __restrict__ abf,
    const float* __restrict__ p1WT, const float* __restrict__ p1b,
    const float* __restrict__ p2WT, const float* __restrict__ p2b,
    const float* __restrict__ ln_a, const float* __restrict__ ln_b)
{
    const int tid = threadIdx.x;
    const int r0 = blockIdx.x * RPB;
    __shared__ float X[RPB][TWOD];
    __shared__ float H1[RPB][FOURD];
    __shared__ float red[4][RPB][2];
    __shared__ float muv[RPB], sgv[RPB];

    for (int idx = tid; idx < RPB * TWOD; idx += 256) {
        int r = idx >> 8, j = idx & 255;
        X[r][j] = xin[(size_t)(r0 + r) * TWOD + j];
    }
    __syncthreads();

    {
        float acc[RPB][2] = {};
        for (int j = 0; j < TWOD; j += 4) {
            float w0[4], w1[4];
#pragma unroll
            for (int jj = 0; jj < 4; ++jj) {
                w0[jj] = p1WT[(j + jj) * FOURD + tid];
                w1[jj] = p1WT[(j + jj) * FOURD + tid + 256];
            }
#pragma unroll
            for (int r = 0; r < RPB; ++r) {
                float x[4] __attribute__((aligned(16)));
                *(float4*)x = *(const float4*)&X[r][j];
#pragma unroll
                for (int jj = 0; jj < 4; ++jj) {
                    acc[r][0] += x[jj] * w0[jj];
                    acc[r][1] += x[jj] * w1[jj];
                }
            }
        }
        float b0 = p1b[tid], b1 = p1b[tid + 256];
#pragma unroll
        for (int r = 0; r < RPB; ++r) {
            H1[r][tid]       = fmaxf(acc[r][0] + b0, 0.f);
            H1[r][tid + 256] = fmaxf(acc[r][1] + b1, 0.f);
        }
    }
    __syncthreads();

    float z[RPB];
    {
        float acc[RPB] = {};
        for (int j = 0; j < FOURD; j += 4) {
            float w[4];
#pragma unroll
            for (int jj = 0; jj < 4; ++jj) w[jj] = p2WT[(j + jj) * TWOD + tid];
#pragma unroll
            for (int r = 0; r < RPB; ++r) {
                float h[4] __attribute__((aligned(16)));
                *(float4*)h = *(const float4*)&H1[r][j];
#pragma unroll
                for (int jj = 0; jj < 4; ++jj) acc[r] += h[jj] * w[jj];
            }
        }
        float b = p2b[tid];
#pragma unroll
        for (int r = 0; r < RPB; ++r) z[r] = acc[r] + b + X[r][tid];
    }
    {
        float s[RPB], ss[RPB];
#pragma unroll
        for (int r = 0; r < RPB; ++r) { s[r] = z[r]; ss[r] = z[r] * z[r]; }
#pragma unroll
        for (int off = 1; off < 64; off <<= 1)
#pragma unroll
            for (int r = 0; r < RPB; ++r) {
                s[r]  += __shfl_xor(s[r],  off, 64);
                ss[r] += __shfl_xor(ss[r], off, 64);
            }
        const int wv = tid >> 6, lane = tid & 63;
        if (lane == 0) {
#pragma unroll
            for (int r = 0; r < RPB; ++r) { red[wv][r][0] = s[r]; red[wv][r][1] = ss[r]; }
        }
        __syncthreads();
        if (tid < RPB) {
            float st  = red[0][tid][0] + red[1][tid][0] + red[2][tid][0] + red[3][tid][0];
            float sst = red[0][tid][1] + red[1][tid][1] + red[2][tid][1] + red[3][tid][1];
            float mu  = st / (float)TWOD;
            float var = fmaxf((sst - (float)TWOD * mu * mu) / ((float)TWOD - 1.f), 0.f);
            muv[tid] = mu; sgv[tid] = sqrtf(var);
        }
        __syncthreads();
    }
#pragma unroll
    for (int r = 0; r < RPB; ++r) {
        float o = (z[r] - muv[r]) / (sgv[r] + 1e-3f) * ln_a[tid] + ln_b[tid];
        xout[(size_t)(r0 + r) * TWOD + tid] = o;
        if (abf) abf[(size_t)(r0 + r) * KTOT + tid] = f2bf(o);
    }
}

// ---------------- K4a: LSTM gates via bf16 MFMA, fused cell update -------------
// nkt = number of 32-wide K tiles. Step 0 runs with nkt=8 (K=256): h_r=0, c=0,
// so the h|r two-thirds of K would multiply zeros — skip them entirely.
__global__ __launch_bounds__(256) void k_lstm_mfma(
    const unsigned short* __restrict__ Abf,
    const unsigned short* __restrict__ Wbf,
    const float* __restrict__ biasR,
    float* __restrict__ cst, float* __restrict__ hbuf,
    const int nkt)
{
    __shared__ __align__(16) unsigned short As[128 * 32];
    __shared__ __align__(16) unsigned short Bs[128 * 32];
    const int tid  = threadIdx.x;
    const int wave = tid >> 6, lane = tid & 63;
    const int quad = lane >> 4, m15 = lane & 15;
    const int m0 = blockIdx.x * 128;
    const int n0 = blockIdx.y * 128;
    const int wm = wave >> 1, wn = wave & 1;
    const int lrow = lane >> 2, lslot = lane & 3;

    f32x4 acc[4][4] = {};

    for (int kt = 0; kt < nkt; ++kt) {
        const int k0 = kt * 32;
        __syncthreads();
#pragma unroll
        for (int t = 0; t < 2; ++t) {
            int c = wave * 2 + t;
            int row = c * 16 + lrow;
            int kg = lslot ^ ((row >> 1) & 3);
            gload_lds16(Abf + (size_t)(m0 + row) * KTOT + k0 + kg * 8, As + c * 512);
            gload_lds16(Wbf + (size_t)(n0 + row) * KTOT + k0 + kg * 8, Bs + c * 512);
        }
        __syncthreads();

        bf16x8 fa[4], fb[4];
#pragma unroll
        for (int mi = 0; mi < 4; ++mi) {
            int ra = wm * 64 + mi * 16 + m15;
            int sa = quad ^ ((ra >> 1) & 3);
            fa[mi] = *(const bf16x8*)(As + ra * 32 + sa * 8);
            int rb = wn * 64 + mi * 16 + m15;
            int sb = quad ^ ((rb >> 1) & 3);
            fb[mi] = *(const bf16x8*)(Bs + rb * 32 + sb * 8);
        }
#pragma unroll
        for (int mi = 0; mi < 4; ++mi)
#pragma unroll
            for (int ni = 0; ni < 4; ++ni)
                acc[mi][ni] = __builtin_amdgcn_mfma_f32_16x16x32_bf16(fa[mi], fb[ni], acc[mi][ni], 0, 0, 0);
    }

    const int u = ((n0 + wn * 64) >> 2) + m15;
    float bg[4];
#pragma unroll
    for (int g = 0; g < 4; ++g) bg[g] = biasR[n0 + wn * 64 + g * 16 + m15];
#pragma unroll
    for (int mi = 0; mi < 4; ++mi) {
#pragma unroll
        for (int r = 0; r < 4; ++r) {
            int gm = m0 + wm * 64 + mi * 16 + quad * 4 + r;
            size_t cidx = (size_t)gm * ULIVE + u;
            float pi = acc[mi][0][r] + bg[0];
            float pf = acc[mi][1][r] + bg[1];
            float pg = acc[mi][2][r] + bg[2];
            float po = acc[mi][3][r] + bg[3];
            float cn = sigmoidf_(pf) * cst[cidx] + sigmoidf_(pi) * tanhf(pg);
            cst[cidx]  = cn;
            hbuf[cidx] = sigmoidf_(po) * tanhf(cn);
        }
    }
}

// ---------------- K4b: h, attention over support, write bf16 h|r ---------------
__global__ __launch_bounds__(256) void k_lstm_attn(
    const float* __restrict__ qg, const float* __restrict__ hbuf,
    const float* __restrict__ sg, unsigned short* __restrict__ Abf,
    float* __restrict__ hfin)
{
    const int tid = threadIdx.x;
    const int p   = blockIdx.y;
    const int wv = tid >> 6, lane = tid & 63;
    __shared__ float sgl[FEWN][TWOD];
    for (int idx = tid; idx < FEWN * TWOD; idx += 256)
        sgl[idx >> 8][idx & 255] = sg[p * FEWN * TWOD + idx];
    __syncthreads();
    const int j0 = lane * 4;
    for (int rr = 0; rr < 8; ++rr) {
        int row = blockIdx.x * 32 + wv * 8 + rr;
        size_t g = (size_t)p * BQ + row;
        float4 q4 = *(const float4*)(qg + g * TWOD + j0);
        float4 t4 = *(const float4*)(hbuf + g * ULIVE + j0);
        float h[4] __attribute__((aligned(16))) = {q4.x + t4.x, q4.y + t4.y, q4.z + t4.z, q4.w + t4.w};
        float sv[FEWN][4] __attribute__((aligned(16)));
        float pa[FEWN];
#pragma unroll
        for (int f = 0; f < FEWN; ++f) {
            *(float4*)sv[f] = *(const float4*)&sgl[f][j0];
            pa[f] = h[0] * sv[f][0] + h[1] * sv[f][1] + h[2] * sv[f][2] + h[3] * sv[f][3];
        }
#pragma unroll
        for (int off = 1; off < 64; off <<= 1)
#pragma unroll
            for (int f = 0; f < FEWN; ++f) pa[f] += __shfl_xor(pa[f], off, 64);
        float mx = pa[0];
#pragma unroll
        for (int f = 1; f < FEWN; ++f) mx = fmaxf(mx, pa[f]);
        float sum = 0.f, e[FEWN];
#pragma unroll
        for (int f = 0; f < FEWN; ++f) { e[f] = expf(pa[f] - mx); sum += e[f]; }
        float inv = 1.f / sum;
        float r4[4] __attribute__((aligned(16))) = {0.f, 0.f, 0.f, 0.f};
#pragma unroll
        for (int f = 0; f < FEWN; ++f) {
            float a = e[f] * inv;
#pragma unroll
            for (int q = 0; q < 4; ++q) r4[q] += a * sv[f][q];
        }
        unsigned short tb[4] __attribute__((aligned(8)));
#pragma unroll
        for (int q = 0; q < 4; ++q) tb[q] = f2bf(h[q]);
        *(uint2*)(Abf + g * KTOT + TWOD + j0) = *(uint2*)tb;
#pragma unroll
        for (int q = 0; q < 4; ++q) tb[q] = f2bf(r4[q]);
        *(uint2*)(Abf + g * KTOT + FOURD + j0) = *(uint2*)tb;
        *(float4*)(hfin + g * TWOD + j0) = *(float4*)h;
    }
}

// ---------------- K5: final scores ---------------------------------------------
__global__ __launch_bounds__(256) void k_score(
    const float* __restrict__ hfin, const float* __restrict__ sg, float* __restrict__ out)
{
    const int tid = threadIdx.x;
    const int p   = blockIdx.y;
    __shared__ float sm[TWOD];
    if (tid < TWOD) {
        const float* s = sg + p * FEWN * TWOD + tid;
        sm[tid] = (s[0] + s[TWOD] + s[2 * TWOD] + s[3 * TWOD] + s[4 * TWOD]) / 5.0f;
    }
    __syncthreads();
    const int wv = tid >> 6, lane = tid & 63;
    const int j0 = lane * 4;
    for (int rr = 0; rr < 8; ++rr) {
        int row = blockIdx.x * 32 + wv * 8 + rr;
        const float* h = hfin + ((size_t)p * BQ + row) * TWOD + j0;
        float4 h4 = *(const float4*)h;
        float4 s4 = *(const float4*)&sm[j0];
        float pv = h4.x * s4.x + h4.y * s4.y + h4.z * s4.z + h4.w * s4.w;
#pragma unroll
        for (int off = 1; off < 64; off <<= 1) pv += __shfl_xor(pv, off, 64);
        if (lane == 0) out[p * BQ + row] = pv;
    }
}

extern "C" void kernel_launch(void* const* d_in, const int* in_sizes, int n_in,
                              void* d_out, int out_size, void* d_ws, size_t ws_size,
                              hipStream_t stream)
{
    const float* emb     = (const float*)d_in[0];
    const float* emb_var = (const float*)d_in[1];
    const float* nW      = (const float*)d_in[2];
    const float* nWb     = (const float*)d_in[3];
    const float* nu      = (const float*)d_in[4];
    const float* nub     = (const float*)d_in[5];
    const float* nvW     = (const float*)d_in[6];
    const float* nvWb    = (const float*)d_in[7];
    const float* nvu     = (const float*)d_in[8];
    const float* nvub    = (const float*)d_in[9];
    const float* p1W     = (const float*)d_in[10];
    const float* p1b     = (const float*)d_in[11];
    const float* p2W     = (const float*)d_in[12];
    const float* p2b     = (const float*)d_in[13];
    const float* ln_a    = (const float*)d_in[14];
    const float* ln_b    = (const float*)d_in[15];
    const float* Wih     = (const float*)d_in[16];
    const float* Whh     = (const float*)d_in[17];
    const float* bih     = (const float*)d_in[18];
    const float* bhh     = (const float*)d_in[19];
    const int* q_left    = (const int*)d_in[20];
    const int* q_right   = (const int*)d_in[21];
    const int* s_left    = (const int*)d_in[22];
    const int* s_right   = (const int*)d_in[23];

    float* ws = (float*)d_ws;
    size_t o = 0;
    float* p1WT     = ws + o; o += FOURD * TWOD;
    float* p2WT     = ws + o; o += FOURD * TWOD;
    float* biasR    = ws + o; o += NGATE;
    float* query    = ws + o; o += (size_t)2 * BQ * TWOD;    // reused as hfin
    float* supportB = ws + o; o += 2 * FEWN * TWOD;
    float* qg       = ws + o; o += (size_t)2 * BQ * TWOD;
    float* sg       = ws + o; o += 2 * FEWN * TWOD;
    float* cst      = ws + o; o += (size_t)2 * BQ * ULIVE;
    float* hbuf     = ws + o; o += (size_t)2 * BQ * ULIVE;
    unsigned short* Wbf = (unsigned short*)(ws + o); o += (size_t)NGATE * KTOT / 2;
    unsigned short* Abf = (unsigned short*)(ws + o); o += (size_t)2 * BQ * KTOT / 2;
    unsigned short* Nbf = (unsigned short*)(ws + o); o += (size_t)2 * DD * TWOD / 2;
    float* hfin     = query;

    // cst must be zero for step 0 (f-gate multiplies it). Abf memset dropped:
    // step 0 runs K=256 (never reads h|r), and k_lstm_attn fully writes h|r
    // for every row before step 1 reads it.
    hipMemsetAsync(cst, 0, (size_t)2 * BQ * ULIVE * sizeof(float), stream);

    k_prep<<<dim3(1024), dim3(256), 0, stream>>>(Wih, Whh, bih, bhh, p1W, p2W, nW, nvW,
                                                 Wbf, biasR, p1WT, p2WT, Nbf);
    k_neighbor_v7<<<dim3((TOTU + UPB - 1) / UPB, 2), dim3(256), 0, stream>>>(
        emb, emb_var, Nbf, nWb, nu, nvWb, nvu,
        q_left, q_right, s_left, s_right, query, supportB);
    k_supenc<8><<<dim3(2 * BQ / 8), dim3(256), 0, stream>>>(query, qg, Abf, p1WT, p1b, p2WT, p2b, ln_a, ln_b);
    k_supenc<1><<<dim3(2 * FEWN), dim3(256), 0, stream>>>(supportB, sg, (unsigned short*)nullptr,
                                                          p1WT, p1b, p2WT, p2b, ln_a, ln_b);
    for (int s = 0; s < 4; ++s) {
        k_lstm_mfma<<<dim3(2 * BQ / 128, NGATE / 128), dim3(256), 0, stream>>>(
            Abf, Wbf, biasR, cst, hbuf, s == 0 ? TWOD / 32 : KTOT / 32);
        k_lstm_attn<<<dim3(BQ / 32, 2), dim3(256), 0, stream>>>(qg, hbuf, sg, Abf, hfin);
    }
    k_score<<<dim3(BQ / 32, 2), dim3(256), 0, stream>>>(hfin, sg, (float*)d_out);
}

// Round 4
// 733.962 us; speedup vs baseline: 1.0179x; 1.0179x over previous
//
#include <hip/hip_runtime.h>
#include <math.h>

#define DD    128
#define TWOD  256
#define FOURD 512
#define NBN   30
#define BQ    4096
#define FEWN  5
#define NSYM  200000
#define KTOT  768    // 256 (query) + 256 (h) + 256 (r)
#define NGATE 1024   // 256 live units x 4 gates (units 256..511 are dead)
#define ULIVE 256
#define TOTU  (2 * BQ + 2 * FEWN)   // 8202 row-units
#define UPB   8                      // units per block (neighbor kernel, 512 thr)

typedef short bf16x8 __attribute__((ext_vector_type(8)));
typedef float f32x4 __attribute__((ext_vector_type(4)));

__device__ __forceinline__ float sigmoidf_(float x) { return 1.0f / (1.0f + expf(-x)); }

// fast tanh: 1 - 2/(e^{2x}+1)  (v_exp + v_rcp; |err| ~1e-6, saturates correctly)
__device__ __forceinline__ float ftanh(float x) {
    float e = __expf(2.0f * x);
    return 1.0f - 2.0f / (e + 1.0f);
}

__device__ __forceinline__ unsigned short f2bf(float f) {
    unsigned int u = __float_as_uint(f);
    unsigned int r = (u + 0x7fffu + ((u >> 16) & 1u)) >> 16;
    return (unsigned short)r;
}

__device__ __forceinline__ float bf2f(unsigned short s) {
    return __uint_as_float(((unsigned int)s) << 16);
}

// pack 8 fp32 -> bf16x8 (round-to-nearest-ish)
__device__ __forceinline__ bf16x8 pack8(float4 a, float4 b) {
    union { bf16x8 v; unsigned int u[4]; } r;
    r.u[0] = ((__float_as_uint(a.x) + 0x8000u) >> 16) | ((__float_as_uint(a.y) + 0x8000u) & 0xffff0000u);
    r.u[1] = ((__float_as_uint(a.z) + 0x8000u) >> 16) | ((__float_as_uint(a.w) + 0x8000u) & 0xffff0000u);
    r.u[2] = ((__float_as_uint(b.x) + 0x8000u) >> 16) | ((__float_as_uint(b.y) + 0x8000u) & 0xffff0000u);
    r.u[3] = ((__float_as_uint(b.z) + 0x8000u) >> 16) | ((__float_as_uint(b.w) + 0x8000u) & 0xffff0000u);
    return r.v;
}

__device__ __forceinline__ void gload_lds16(const void* g, void* l) {
    __builtin_amdgcn_global_load_lds((const __attribute__((address_space(1))) unsigned int*)g,
                                     (__attribute__((address_space(3))) unsigned int*)l,
                                     16, 0, 0);
}

// ---------------- K-1: fp32 -> bf16 embedding tables (streaming) ---------------
// Halves the random-gather granule (512B -> 256B row) and makes both tables
// (102 MB) L3-resident for the neighbor kernel's gathers.
__global__ __launch_bounds__(256) void k_conv(
    const float* __restrict__ emb, const float* __restrict__ emb_var,
    unsigned short* __restrict__ embB, unsigned short* __restrict__ evB)
{
    const size_t total = (size_t)(NSYM + 1) * DD / 8;
    size_t idx = (size_t)blockIdx.x * 256 + threadIdx.x;
    size_t stride = (size_t)gridDim.x * 256;
    for (size_t i = idx; i < total; i += stride) {
        const float* s = emb + i * 8;
        float4 a = *(const float4*)s, b = *(const float4*)(s + 4);
        *(bf16x8*)(embB + i * 8) = pack8(a, b);
        const float* s2 = emb_var + i * 8;
        float4 a2 = *(const float4*)s2, b2 = *(const float4*)(s2 + 4);
        *(bf16x8*)(evB + i * 8) = pack8(a2, b2);
    }
}

// ---------------- K0: one-time weight prep -------------------------------------
__global__ __launch_bounds__(256) void k_prep(
    const float* __restrict__ Wih, const float* __restrict__ Whh,
    const float* __restrict__ bih, const float* __restrict__ bhh,
    const float* __restrict__ p1W, const float* __restrict__ p2W,
    const float* __restrict__ nW, const float* __restrict__ nvW,
    unsigned short* __restrict__ Wbf, float* __restrict__ biasR,
    float* __restrict__ p1WT, float* __restrict__ p2WT,
    unsigned short* __restrict__ Nbf)
{
    int idx = blockIdx.x * 256 + threadIdx.x;
    int stride = gridDim.x * 256;
    for (int i = idx; i < NGATE * KTOT; i += stride) {
        int n = i / KTOT, k = i - n * KTOT;
        int blk = n >> 6, rem = n & 63;
        int g = rem >> 4, ul = rem & 15;
        int u = blk * 16 + ul;
        int srcrow = g * 512 + u;
        float v = (k < TWOD) ? Wih[srcrow * TWOD + k] : Whh[srcrow * FOURD + (k - TWOD)];
        Wbf[i] = f2bf(v);
    }
    for (int n = idx; n < NGATE; n += stride) {
        int blk = n >> 6, rem = n & 63;
        int g = rem >> 4, ul = rem & 15;
        int u = blk * 16 + ul;
        int srcrow = g * 512 + u;
        biasR[n] = bih[srcrow] + bhh[srcrow];
    }
    for (int i = idx; i < FOURD * TWOD; i += stride) {
        int o = i / TWOD, j = i % TWOD;
        p1WT[j * FOURD + o] = p1W[o * TWOD + j];
    }
    for (int i = idx; i < TWOD * FOURD; i += stride) {
        int o = i / FOURD, j = i % FOURD;
        p2WT[j * TWOD + o] = p2W[o * FOURD + j];
    }
    for (int i = idx; i < 2 * DD * TWOD; i += stride) {
        float v = (i < DD * TWOD) ? nW[i] : nvW[i - DD * TWOD];
        Nbf[i] = f2bf(v);
    }
}

// ---------------- K1 v8: neighbor encoder, joint bf16 gather, 512 threads ------
// 8 waves: path = wave>>2, n-slice = (wave&3)*32. Both paths in ONE block so
// the 4 staged row-groups (rel_e, ent_e, rel_v, ent_v) are fetched once and
// ent_e is shared by both paths' pooling (v4's traffic profile, ~half v7's).
// Gather = bf16 rows (256 B) via global_load_lds direct-to-LDS; source chunk
// index pre-swizzled (chunk ^ (row&15)) so LDS stays linear while frag reads
// and pooling are bank-spread (rule 21: same involution on source and read).
// Rows 30,31 stage the NSYM pad row (zeros). A-frag = one 16B LDS read, no
// fp32->bf16 pack in the hot loop. Bf per wave = 64 VGPR -> ~115 regs ->
// 2 blocks/CU (16 waves) by VGPR; LDS ~39 KB is not the limiter.
__global__ __launch_bounds__(512, 4) void k_neighbor_v8(
    const unsigned short* __restrict__ embB, const unsigned short* __restrict__ evB,
    const unsigned short* __restrict__ Nbf,
    const float* __restrict__ nWb, const float* __restrict__ nu,
    const float* __restrict__ nvWb, const float* __restrict__ nvu,
    const int* __restrict__ q_left, const int* __restrict__ q_right,
    const int* __restrict__ s_left, const int* __restrict__ s_right,
    float* __restrict__ query, float* __restrict__ support)
{
    const int tid  = threadIdx.x;
    const int wave = tid >> 6, lane = tid & 63;
    const int quad = lane >> 4, m15 = lane & 15;
    const int path = wave >> 2;          // 0: mean, 1: var
    const int wq   = wave & 3;           // n-slice within path
    const int u0   = blockIdx.x * UPB;

    __shared__ __align__(16) unsigned short Gb[4 * 32 * DD];   // 4 groups x 32 rows x 256B
    __shared__ int   sidxL[UPB][64];
    __shared__ float aP[2][4][32];
    __shared__ float attL[2][32];
    __shared__ float poolP[2][2][DD];

    // ---- block init: neighbor indices for all UPB units (512 = UPB*64) ----
    {
        int un = tid >> 6, i = tid & 63;
        int uu_ = u0 + un; if (uu_ >= TOTU) uu_ = TOTU - 1;
        const int* conn;
        if (uu_ < BQ)                 conn = q_left  + uu_ * (NBN * 2);
        else if (uu_ < 2 * BQ)        conn = q_right + (uu_ - BQ) * (NBN * 2);
        else if (uu_ < 2 * BQ + FEWN) conn = s_left  + (uu_ - 2 * BQ) * (NBN * 2);
        else                          conn = s_right + (uu_ - 2 * BQ - FEWN) * (NBN * 2);
        sidxL[un][i] = (i < NBN * 2) ? conn[i] : NSYM;   // rows 30,31 -> pad row (zeros)
    }

    // ---- per-wave constants: B fragments (64 VGPR), u & bias slices ----
    const unsigned short* Bw = Nbf + (size_t)path * DD * TWOD;
    const float* Wb = path ? nvWb : nWb;
    const float* uu = path ? nvu  : nu;
    bf16x8 Bf[2][8];
    float nb[2], un_[2];
#pragma unroll
    for (int t = 0; t < 2; ++t) {
        int n = wq * 32 + t * 16 + m15;
#pragma unroll
        for (int kt = 0; kt < 8; ++kt)
            Bf[t][kt] = *(const bf16x8*)(Bw + n * TWOD + kt * 32 + quad * 8);
        nb[t] = Wb[n];
        un_[t] = uu[n];
    }
    __syncthreads();                       // sidx visible

    for (int r = 0; r < UPB; ++r) {
        const int uidx = u0 + r;

        // ---- stage: group g = wave>>1, row-half h = wave&1; 4 instrs/wave ----
        {
            const int g = wave >> 1, h = wave & 1;
            const unsigned short* table = (g < 2) ? embB : evB;
            const int side = g & 1;
            const int rs = lane >> 4, c = lane & 15;
#pragma unroll
            for (int i = 0; i < 4; ++i) {
                const int row = h * 16 + i * 4 + rs;
                const int sym = sidxL[r][2 * row + side];
                const unsigned short* src = table + (size_t)sym * DD + ((c ^ (row & 15)) << 3);
                gload_lds16(src, &Gb[(g * 32 + h * 16 + i * 4) * DD]);
            }
        }
        __syncthreads();                   // S1: staging visible (vmcnt drain)

        // ---- MFMA: S[32m x 32n per wave] = cat * W_p^T ----
        const int gA = path ? 2 : 0;       // rel group
        const int gB = path ? 3 : 1;       // ent group
        f32x4 acc[2][2] = {};
#pragma unroll
        for (int kt = 0; kt < 8; ++kt) {
            const int g = (kt < 4) ? gA : gB;
            bf16x8 fa[2];
#pragma unroll
            for (int mt = 0; mt < 2; ++mt) {
                const int row = mt * 16 + m15;
                const int ch = ((kt & 3) * 4 + quad) ^ (row & 15);
                fa[mt] = *(const bf16x8*)&Gb[(g * 32 + row) * DD + ch * 8];
            }
#pragma unroll
            for (int mt = 0; mt < 2; ++mt)
#pragma unroll
                for (int nt = 0; nt < 2; ++nt)
                    acc[mt][nt] = __builtin_amdgcn_mfma_f32_16x16x32_bf16(fa[mt], Bf[nt][kt], acc[mt][nt], 0, 0, 0);
        }

        // ---- epilogue: partial a[m] = sum_n u[n]*tanh(S+b) over 32-n slice ----
        {
            float part[2][4];
#pragma unroll
            for (int mt = 0; mt < 2; ++mt)
#pragma unroll
                for (int rr = 0; rr < 4; ++rr) {
                    float s = 0.f;
#pragma unroll
                    for (int nt = 0; nt < 2; ++nt)
                        s += un_[nt] * ftanh(acc[mt][nt][rr] + nb[nt]);
                    part[mt][rr] = s;
                }
#pragma unroll
            for (int off = 1; off < 16; off <<= 1)
#pragma unroll
                for (int mt = 0; mt < 2; ++mt)
#pragma unroll
                    for (int rr = 0; rr < 4; ++rr)
                        part[mt][rr] += __shfl_xor(part[mt][rr], off, 64);
            if (m15 == 0) {
#pragma unroll
                for (int mt = 0; mt < 2; ++mt)
#pragma unroll
                    for (int rr = 0; rr < 4; ++rr)
                        aP[path][wq][mt * 16 + quad * 4 + rr] = part[mt][rr];
            }
        }
        __syncthreads();                   // S2

        // ---- softmax over 30 neighbors: waves 0 (p0) and 4 (p1) ----
        if ((wave & 3) == 0 && lane < 32) {
            const int p = path;
            float sc = (lane < NBN) ? aP[p][0][lane] + aP[p][1][lane] + aP[p][2][lane] + aP[p][3][lane]
                                    : -1e30f;
            float mx = sc;
#pragma unroll
            for (int off = 1; off < 32; off <<= 1) mx = fmaxf(mx, __shfl_xor(mx, off, 64));
            float e = (lane < NBN) ? __expf(sc - mx) : 0.f;
            float sum = e;
#pragma unroll
            for (int off = 1; off < 32; off <<= 1) sum += __shfl_xor(sum, off, 64);
            attL[p][lane] = e / sum;
        }
        __syncthreads();                   // S3

        // ---- pool ent_e (group 1, bf16, shared by both paths), split-k ----
        {
            const int p = tid >> 8;          // path
            const int half = (tid >> 7) & 1;
            const int d = tid & 127;
            const int k0 = half * 15;
            float pp = 0.f;
#pragma unroll
            for (int k = k0; k < k0 + 15; ++k) {
                const int ch = (d >> 3) ^ (k & 15);
                pp += attL[p][k] * bf2f(Gb[(32 + k) * DD + ch * 8 + (d & 7)]);
            }
            poolP[p][half][d] = pp;
        }
        __syncthreads();                   // S4: poolP visible; all Gb reads done

        if (tid < 256 && uidx < TOTU) {
            const int p = tid >> 7, d = tid & 127;
            float pool = poolP[p][0][d] + poolP[p][1][d];
            float* dst;
            if (uidx < BQ)                 dst = query   + ((size_t)p * BQ + uidx) * TWOD;
            else if (uidx < 2 * BQ)        dst = query   + ((size_t)p * BQ + (uidx - BQ)) * TWOD + DD;
            else if (uidx < 2 * BQ + FEWN) dst = support + ((size_t)p * FEWN + (uidx - 2 * BQ)) * TWOD;
            else                           dst = support + ((size_t)p * FEWN + (uidx - 2 * BQ - FEWN)) * TWOD + DD;
            dst[d] = ftanh(pool);
        }
        // next iteration's stage writes Gb only after this thread passed S4 ✓
    }
}

// ---------------- K2: support encoder (MLP + residual + layernorm ddof=1) ------
template <int RPB>
__global__ __launch_bounds__(256) void k_supenc(
    const float* __restrict__ xin, float* __restrict__ xout,
    unsigned short* __restrict__ abf,
    const float* __restrict__ p1WT, const float* __restrict__ p1b,
    const float* __restrict__ p2WT, const float* __restrict__ p2b,
    const float* __restrict__ ln_a, const float* __restrict__ ln_b)
{
    const int tid = threadIdx.x;
    const int r0 = blockIdx.x * RPB;
    __shared__ float X[RPB][TWOD];
    __shared__ float H1[RPB][FOURD];
    __shared__ float red[4][RPB][2];
    __shared__ float muv[RPB], sgv[RPB];

    for (int idx = tid; idx < RPB * TWOD; idx += 256) {
        int r = idx >> 8, j = idx & 255;
        X[r][j] = xin[(size_t)(r0 + r) * TWOD + j];
    }
    __syncthreads();

    {
        float acc[RPB][2] = {};
        for (int j = 0; j < TWOD; j += 4) {
            float w0[4], w1[4];
#pragma unroll
            for (int jj = 0; jj < 4; ++jj) {
                w0[jj] = p1WT[(j + jj) * FOURD + tid];
                w1[jj] = p1WT[(j + jj) * FOURD + tid + 256];
            }
#pragma unroll
            for (int r = 0; r < RPB; ++r) {
                float x[4] __attribute__((aligned(16)));
                *(float4*)x = *(const float4*)&X[r][j];
#pragma unroll
                for (int jj = 0; jj < 4; ++jj) {
                    acc[r][0] += x[jj] * w0[jj];
                    acc[r][1] += x[jj] * w1[jj];
                }
            }
        }
        float b0 = p1b[tid], b1 = p1b[tid + 256];
#pragma unroll
        for (int r = 0; r < RPB; ++r) {
            H1[r][tid]       = fmaxf(acc[r][0] + b0, 0.f);
            H1[r][tid + 256] = fmaxf(acc[r][1] + b1, 0.f);
        }
    }
    __syncthreads();

    float z[RPB];
    {
        float acc[RPB] = {};
        for (int j = 0; j < FOURD; j += 4) {
            float w[4];
#pragma unroll
            for (int jj = 0; jj < 4; ++jj) w[jj] = p2WT[(j + jj) * TWOD + tid];
#pragma unroll
            for (int r = 0; r < RPB; ++r) {
                float h[4] __attribute__((aligned(16)));
                *(float4*)h = *(const float4*)&H1[r][j];
#pragma unroll
                for (int jj = 0; jj < 4; ++jj) acc[r] += h[jj] * w[jj];
            }
        }
        float b = p2b[tid];
#pragma unroll
        for (int r = 0; r < RPB; ++r) z[r] = acc[r] + b + X[r][tid];
    }
    {
        float s[RPB], ss[RPB];
#pragma unroll
        for (int r = 0; r < RPB; ++r) { s[r] = z[r]; ss[r] = z[r] * z[r]; }
#pragma unroll
        for (int off = 1; off < 64; off <<= 1)
#pragma unroll
            for (int r = 0; r < RPB; ++r) {
                s[r]  += __shfl_xor(s[r],  off, 64);
                ss[r] += __shfl_xor(ss[r], off, 64);
            }
        const int wv = tid >> 6, lane = tid & 63;
        if (lane == 0) {
#pragma unroll
            for (int r = 0; r < RPB; ++r) { red[wv][r][0] = s[r]; red[wv][r][1] = ss[r]; }
        }
        __syncthreads();
        if (tid < RPB) {
            float st  = red[0][tid][0] + red[1][tid][0] + red[2][tid][0] + red[3][tid][0];
            float sst = red[0][tid][1] + red[1][tid][1] + red[2][tid][1] + red[3][tid][1];
            float mu  = st / (float)TWOD;
            float var = fmaxf((sst - (float)TWOD * mu * mu) / ((float)TWOD - 1.f), 0.f);
            muv[tid] = mu; sgv[tid] = sqrtf(var);
        }
        __syncthreads();
    }
#pragma unroll
    for (int r = 0; r < RPB; ++r) {
        float o = (z[r] - muv[r]) / (sgv[r] + 1e-3f) * ln_a[tid] + ln_b[tid];
        xout[(size_t)(r0 + r) * TWOD + tid] = o;
        if (abf) abf[(size_t)(r0 + r) * KTOT + tid] = f2bf(o);
    }
}

// ---------------- K4a: LSTM gates via bf16 MFMA, fused cell update -------------
// nkt = number of 32-wide K tiles. Step 0 runs with nkt=8 (K=256): h_r=0, c=0,
// so the h|r two-thirds of K would multiply zeros — skip them entirely.
__global__ __launch_bounds__(256) void k_lstm_mfma(
    const unsigned short* __restrict__ Abf,
    const unsigned short* __restrict__ Wbf,
    const float* __restrict__ biasR,
    float* __restrict__ cst, float* __restrict__ hbuf,
    const int nkt)
{
    __shared__ __align__(16) unsigned short As[128 * 32];
    __shared__ __align__(16) unsigned short Bs[128 * 32];
    const int tid  = threadIdx.x;
    const int wave = tid >> 6, lane = tid & 63;
    const int quad = lane >> 4, m15 = lane & 15;
    const int m0 = blockIdx.x * 128;
    const int n0 = blockIdx.y * 128;
    const int wm = wave >> 1, wn = wave & 1;
    const int lrow = lane >> 2, lslot = lane & 3;

    f32x4 acc[4][4] = {};

    for (int kt = 0; kt < nkt; ++kt) {
        const int k0 = kt * 32;
        __syncthreads();
#pragma unroll
        for (int t = 0; t < 2; ++t) {
            int c = wave * 2 + t;
            int row = c * 16 + lrow;
            int kg = lslot ^ ((row >> 1) & 3);
            gload_lds16(Abf + (size_t)(m0 + row) * KTOT + k0 + kg * 8, As + c * 512);
            gload_lds16(Wbf + (size_t)(n0 + row) * KTOT + k0 + kg * 8, Bs + c * 512);
        }
        __syncthreads();

        bf16x8 fa[4], fb[4];
#pragma unroll
        for (int mi = 0; mi < 4; ++mi) {
            int ra = wm * 64 + mi * 16 + m15;
            int sa = quad ^ ((ra >> 1) & 3);
            fa[mi] = *(const bf16x8*)(As + ra * 32 + sa * 8);
            int rb = wn * 64 + mi * 16 + m15;
            int sb = quad ^ ((rb >> 1) & 3);
            fb[mi] = *(const bf16x8*)(Bs + rb * 32 + sb * 8);
        }
#pragma unroll
        for (int mi = 0; mi < 4; ++mi)
#pragma unroll
            for (int ni = 0; ni < 4; ++ni)
                acc[mi][ni] = __builtin_amdgcn_mfma_f32_16x16x32_bf16(fa[mi], fb[ni], acc[mi][ni], 0, 0, 0);
    }

    const int u = ((n0 + wn * 64) >> 2) + m15;
    float bg[4];
#pragma unroll
    for (int g = 0; g < 4; ++g) bg[g] = biasR[n0 + wn * 64 + g * 16 + m15];
#pragma unroll
    for (int mi = 0; mi < 4; ++mi) {
#pragma unroll
        for (int r = 0; r < 4; ++r) {
            int gm = m0 + wm * 64 + mi * 16 + quad * 4 + r;
            size_t cidx = (size_t)gm * ULIVE + u;
            float pi = acc[mi][0][r] + bg[0];
            float pf = acc[mi][1][r] + bg[1];
            float pg = acc[mi][2][r] + bg[2];
            float po = acc[mi][3][r] + bg[3];
            float cn = sigmoidf_(pf) * cst[cidx] + sigmoidf_(pi) * tanhf(pg);
            cst[cidx]  = cn;
            hbuf[cidx] = sigmoidf_(po) * tanhf(cn);
        }
    }
}

// ---------------- K4b: h, attention over support, write bf16 h|r ---------------
__global__ __launch_bounds__(256) void k_lstm_attn(
    const float* __restrict__ qg, const float* __restrict__ hbuf,
    const float* __restrict__ sg, unsigned short* __restrict__ Abf,
    float* __restrict__ hfin)
{
    const int tid = threadIdx.x;
    const int p   = blockIdx.y;
    const int wv = tid >> 6, lane = tid & 63;
    __shared__ float sgl[FEWN][TWOD];
    for (int idx = tid; idx < FEWN * TWOD; idx += 256)
        sgl[idx >> 8][idx & 255] = sg[p * FEWN * TWOD + idx];
    __syncthreads();
    const int j0 = lane * 4;
    for (int rr = 0; rr < 8; ++rr) {
        int row = blockIdx.x * 32 + wv * 8 + rr;
        size_t g = (size_t)p * BQ + row;
        float4 q4 = *(const float4*)(qg + g * TWOD + j0);
        float4 t4 = *(const float4*)(hbuf + g * ULIVE + j0);
        float h[4] __attribute__((aligned(16))) = {q4.x + t4.x, q4.y + t4.y, q4.z + t4.z, q4.w + t4.w};
        float sv[FEWN][4] __attribute__((aligned(16)));
        float pa[FEWN];
#pragma unroll
        for (int f = 0; f < FEWN; ++f) {
            *(float4*)sv[f] = *(const float4*)&sgl[f][j0];
            pa[f] = h[0] * sv[f][0] + h[1] * sv[f][1] + h[2] * sv[f][2] + h[3] * sv[f][3];
        }
#pragma unroll
        for (int off = 1; off < 64; off <<= 1)
#pragma unroll
            for (int f = 0; f < FEWN; ++f) pa[f] += __shfl_xor(pa[f], off, 64);
        float mx = pa[0];
#pragma unroll
        for (int f = 1; f < FEWN; ++f) mx = fmaxf(mx, pa[f]);
        float sum = 0.f, e[FEWN];
#pragma unroll
        for (int f = 0; f < FEWN; ++f) { e[f] = expf(pa[f] - mx); sum += e[f]; }
        float inv = 1.f / sum;
        float r4[4] __attribute__((aligned(16))) = {0.f, 0.f, 0.f, 0.f};
#pragma unroll
        for (int f = 0; f < FEWN; ++f) {
            float a = e[f] * inv;
#pragma unroll
            for (int q = 0; q < 4; ++q) r4[q] += a * sv[f][q];
        }
        unsigned short tb[4] __attribute__((aligned(8)));
#pragma unroll
        for (int q = 0; q < 4; ++q) tb[q] = f2bf(h[q]);
        *(uint2*)(Abf + g * KTOT + TWOD + j0) = *(uint2*)tb;
#pragma unroll
        for (int q = 0; q < 4; ++q) tb[q] = f2bf(r4[q]);
        *(uint2*)(Abf + g * KTOT + FOURD + j0) = *(uint2*)tb;
        *(float4*)(hfin + g * TWOD + j0) = *(float4*)h;
    }
}

// ---------------- K5: final scores ---------------------------------------------
__global__ __launch_bounds__(256) void k_score(
    const float* __restrict__ hfin, const float* __restrict__ sg, float* __restrict__ out)
{
    const int tid = threadIdx.x;
    const int p   = blockIdx.y;
    __shared__ float sm[TWOD];
    if (tid < TWOD) {
        const float* s = sg + p * FEWN * TWOD + tid;
        sm[tid] = (s[0] + s[TWOD] + s[2 * TWOD] + s[3 * TWOD] + s[4 * TWOD]) / 5.0f;
    }
    __syncthreads();
    const int wv = tid >> 6, lane = tid & 63;
    const int j0 = lane * 4;
    for (int rr = 0; rr < 8; ++rr) {
        int row = blockIdx.x * 32 + wv * 8 + rr;
        const float* h = hfin + ((size_t)p * BQ + row) * TWOD + j0;
        float4 h4 = *(const float4*)h;
        float4 s4 = *(const float4*)&sm[j0];
        float pv = h4.x * s4.x + h4.y * s4.y + h4.z * s4.z + h4.w * s4.w;
#pragma unroll
        for (int off = 1; off < 64; off <<= 1) pv += __shfl_xor(pv, off, 64);
        if (lane == 0) out[p * BQ + row] = pv;
    }
}

extern "C" void kernel_launch(void* const* d_in, const int* in_sizes, int n_in,
                              void* d_out, int out_size, void* d_ws, size_t ws_size,
                              hipStream_t stream)
{
    const float* emb     = (const float*)d_in[0];
    const float* emb_var = (const float*)d_in[1];
    const float* nW      = (const float*)d_in[2];
    const float* nWb     = (const float*)d_in[3];
    const float* nu      = (const float*)d_in[4];
    const float* nub     = (const float*)d_in[5];
    const float* nvW     = (const float*)d_in[6];
    const float* nvWb    = (const float*)d_in[7];
    const float* nvu     = (const float*)d_in[8];
    const float* nvub    = (const float*)d_in[9];
    const float* p1W     = (const float*)d_in[10];
    const float* p1b     = (const float*)d_in[11];
    const float* p2W     = (const float*)d_in[12];
    const float* p2b     = (const float*)d_in[13];
    const float* ln_a    = (const float*)d_in[14];
    const float* ln_b    = (const float*)d_in[15];
    const float* Wih     = (const float*)d_in[16];
    const float* Whh     = (const float*)d_in[17];
    const float* bih     = (const float*)d_in[18];
    const float* bhh     = (const float*)d_in[19];
    const int* q_left    = (const int*)d_in[20];
    const int* q_right   = (const int*)d_in[21];
    const int* s_left    = (const int*)d_in[22];
    const int* s_right   = (const int*)d_in[23];

    float* ws = (float*)d_ws;
    size_t o = 0;
    float* p1WT     = ws + o; o += FOURD * TWOD;
    float* p2WT     = ws + o; o += FOURD * TWOD;
    float* biasR    = ws + o; o += NGATE;
    float* query    = ws + o; o += (size_t)2 * BQ * TWOD;    // reused as hfin
    float* supportB = ws + o; o += 2 * FEWN * TWOD;
    float* qg       = ws + o; o += (size_t)2 * BQ * TWOD;
    float* sg       = ws + o; o += 2 * FEWN * TWOD;
    float* cst      = ws + o; o += (size_t)2 * BQ * ULIVE;
    float* hbuf     = ws + o; o += (size_t)2 * BQ * ULIVE;
    unsigned short* Wbf = (unsigned short*)(ws + o); o += (size_t)NGATE * KTOT / 2;
    unsigned short* Abf = (unsigned short*)(ws + o); o += (size_t)2 * BQ * KTOT / 2;
    unsigned short* Nbf = (unsigned short*)(ws + o); o += (size_t)2 * DD * TWOD / 2;
    unsigned short* embB = (unsigned short*)(ws + o); o += (size_t)(NSYM + 1) * DD / 2;
    unsigned short* evB  = (unsigned short*)(ws + o); o += (size_t)(NSYM + 1) * DD / 2;
    float* hfin     = query;

    // cst must be zero for step 0 (f-gate multiplies it). Abf memset dropped:
    // step 0 runs K=256 (never reads h|r), and k_lstm_attn fully writes h|r
    // for every row before step 1 reads it.
    hipMemsetAsync(cst, 0, (size_t)2 * BQ * ULIVE * sizeof(float), stream);

    k_conv<<<dim3(2048), dim3(256), 0, stream>>>(emb, emb_var, embB, evB);
    k_prep<<<dim3(1024), dim3(256), 0, stream>>>(Wih, Whh, bih, bhh, p1W, p2W, nW, nvW,
                                                 Wbf, biasR, p1WT, p2WT, Nbf);
    k_neighbor_v8<<<dim3((TOTU + UPB - 1) / UPB), dim3(512), 0, stream>>>(
        embB, evB, Nbf, nWb, nu, nvWb, nvu,
        q_left, q_right, s_left, s_right, query, supportB);
    k_supenc<8><<<dim3(2 * BQ / 8), dim3(256), 0, stream>>>(query, qg, Abf, p1WT, p1b, p2WT, p2b, ln_a, ln_b);
    k_supenc<1><<<dim3(2 * FEWN), dim3(256), 0, stream>>>(supportB, sg, (unsigned short*)nullptr,
                                                          p1WT, p1b, p2WT, p2b, ln_a, ln_b);
    for (int s = 0; s < 4; ++s) {
        k_lstm_mfma<<<dim3(2 * BQ / 128, NGATE / 128), dim3(256), 0, stream>>>(
            Abf, Wbf, biasR, cst, hbuf, s == 0 ? TWOD / 32 : KTOT / 32);
        k_lstm_attn<<<dim3(BQ / 32, 2), dim3(256), 0, stream>>>(qg, hbuf, sg, Abf, hfin);
    }
    k_score<<<dim3(BQ / 32, 2), dim3(256), 0, stream>>>(hfin, sg, (float*)d_out);
}

// Round 5
// 589.993 us; speedup vs baseline: 1.2662x; 1.2440x over previous
//
#include <hip/hip_runtime.h>
#include <math.h>

#define DD    128
#define TWOD  256
#define FOURD 512
#define NBN   30
#define BQ    4096
#define FEWN  5
#define NSYM  200000
#define KTOT  768    // 256 (query) + 256 (h) + 256 (r)
#define NGATE 1024   // 256 live units x 4 gates (units 256..511 are dead)
#define ULIVE 256
#define TOTU  (2 * BQ + 2 * FEWN)   // 8202 row-units
#define UPB   4                      // units per block (neighbor kernel)
#define PSTR  136                    // padded bf16 row stride (128 + 8)

typedef short bf16x8 __attribute__((ext_vector_type(8)));
typedef float f32x4 __attribute__((ext_vector_type(4)));

__device__ __forceinline__ float sigmoidf_(float x) { return 1.0f / (1.0f + expf(-x)); }

// fast tanh: 1 - 2/(e^{2x}+1)  (v_exp + v_rcp; |err| ~1e-6, saturates correctly)
__device__ __forceinline__ float ftanh(float x) {
    float e = __expf(2.0f * x);
    return 1.0f - 2.0f / (e + 1.0f);
}

__device__ __forceinline__ unsigned short f2bf(float f) {
    unsigned int u = __float_as_uint(f);
    unsigned int r = (u + 0x7fffu + ((u >> 16) & 1u)) >> 16;
    return (unsigned short)r;
}

__device__ __forceinline__ float bf2f(unsigned short s) {
    return __uint_as_float(((unsigned int)s) << 16);
}

// pack 8 fp32 -> bf16x8 (round-to-nearest-ish)
__device__ __forceinline__ bf16x8 pack8(float4 a, float4 b) {
    union { bf16x8 v; unsigned int u[4]; } r;
    r.u[0] = ((__float_as_uint(a.x) + 0x8000u) >> 16) | ((__float_as_uint(a.y) + 0x8000u) & 0xffff0000u);
    r.u[1] = ((__float_as_uint(a.z) + 0x8000u) >> 16) | ((__float_as_uint(a.w) + 0x8000u) & 0xffff0000u);
    r.u[2] = ((__float_as_uint(b.x) + 0x8000u) >> 16) | ((__float_as_uint(b.y) + 0x8000u) & 0xffff0000u);
    r.u[3] = ((__float_as_uint(b.z) + 0x8000u) >> 16) | ((__float_as_uint(b.w) + 0x8000u) & 0xffff0000u);
    return r.v;
}

__device__ __forceinline__ void gload_lds16(const void* g, void* l) {
    __builtin_amdgcn_global_load_lds((const __attribute__((address_space(1))) unsigned int*)g,
                                     (__attribute__((address_space(3))) unsigned int*)l,
                                     16, 0, 0);
}

// ---------------- K0: one-time weight prep -------------------------------------
__global__ __launch_bounds__(256) void k_prep(
    const float* __restrict__ Wih, const float* __restrict__ Whh,
    const float* __restrict__ bih, const float* __restrict__ bhh,
    const float* __restrict__ p1W, const float* __restrict__ p2W,
    const float* __restrict__ nW, const float* __restrict__ nvW,
    unsigned short* __restrict__ Wbf, float* __restrict__ biasR,
    float* __restrict__ p1WT, float* __restrict__ p2WT,
    unsigned short* __restrict__ Nbf)
{
    int idx = blockIdx.x * 256 + threadIdx.x;
    int stride = gridDim.x * 256;
    for (int i = idx; i < NGATE * KTOT; i += stride) {
        int n = i / KTOT, k = i - n * KTOT;
        int blk = n >> 6, rem = n & 63;
        int g = rem >> 4, ul = rem & 15;
        int u = blk * 16 + ul;
        int srcrow = g * 512 + u;
        float v = (k < TWOD) ? Wih[srcrow * TWOD + k] : Whh[srcrow * FOURD + (k - TWOD)];
        Wbf[i] = f2bf(v);
    }
    for (int n = idx; n < NGATE; n += stride) {
        int blk = n >> 6, rem = n & 63;
        int g = rem >> 4, ul = rem & 15;
        int u = blk * 16 + ul;
        int srcrow = g * 512 + u;
        biasR[n] = bih[srcrow] + bhh[srcrow];
    }
    for (int i = idx; i < FOURD * TWOD; i += stride) {
        int o = i / TWOD, j = i % TWOD;
        p1WT[j * FOURD + o] = p1W[o * TWOD + j];
    }
    for (int i = idx; i < TWOD * FOURD; i += stride) {
        int o = i / FOURD, j = i % FOURD;
        p2WT[j * TWOD + o] = p2W[o * FOURD + j];
    }
    for (int i = idx; i < 2 * DD * TWOD; i += stride) {
        float v = (i < DD * TWOD) ? nW[i] : nvW[i - DD * TWOD];
        Nbf[i] = f2bf(v);
    }
}

// ---------------- K1 v4: neighbor encoder, both paths, LDS-staged gather -------
// (Best measured variant: 154 us. v5-v8 restructurings all regressed; this
// barrier-locked structure is latency-bound but its alternatives are worse.)
__global__ __launch_bounds__(256, 2) void k_neighbor_v4(
    const float* __restrict__ emb, const float* __restrict__ emb_var,
    const unsigned short* __restrict__ Nbf,
    const float* __restrict__ nWb, const float* __restrict__ nu,
    const float* __restrict__ nvWb, const float* __restrict__ nvu,
    const int* __restrict__ q_left, const int* __restrict__ q_right,
    const int* __restrict__ s_left, const int* __restrict__ s_right,
    float* __restrict__ query, float* __restrict__ support)
{
    const int tid  = threadIdx.x;
    const int wave = tid >> 6, lane = tid & 63;
    const int quad = lane >> 4, m15 = lane & 15;
    const int pw   = wave >> 1;          // path of this wave (MFMA phase)
    const int wn   = wave & 1;           // n-half
    const int u0   = blockIdx.x * UPB;

    __shared__ __align__(16) unsigned short Sg[4 * 32 * PSTR];  // 4 groups x 32 rows
    __shared__ int   sidxL[UPB][64];
    __shared__ float aP[2][2][32];
    __shared__ float attL[2][32];

    // ---- block init: neighbor indices for all UPB units ----
    {
        int un = tid >> 6, i = tid & 63;
        int uu_ = u0 + un; if (uu_ >= TOTU) uu_ = TOTU - 1;
        const int* conn;
        if (uu_ < BQ)                 conn = q_left  + uu_ * (NBN * 2);
        else if (uu_ < 2 * BQ)        conn = q_right + (uu_ - BQ) * (NBN * 2);
        else if (uu_ < 2 * BQ + FEWN) conn = s_left  + (uu_ - 2 * BQ) * (NBN * 2);
        else                          conn = s_right + (uu_ - 2 * BQ - FEWN) * (NBN * 2);
        sidxL[un][i] = (i < NBN * 2) ? conn[i] : NSYM;
    }

    // ---- per-wave constants: B fragments (128 VGPR), u & bias slices ----
    const unsigned short* Bw = Nbf + (size_t)pw * DD * TWOD;
    const float* Wb = pw ? nvWb : nWb;
    const float* uu = pw ? nvu  : nu;
    bf16x8 Bf[4][8];
    float nb[4], un_[4];
#pragma unroll
    for (int t = 0; t < 4; ++t) {
        int n = wn * 64 + t * 16 + m15;
#pragma unroll
        for (int kt = 0; kt < 8; ++kt)
            Bf[t][kt] = *(const bf16x8*)(Bw + n * TWOD + kt * 32 + quad * 8);
        nb[t] = Wb[n];
        un_[t] = uu[n];
    }
    __syncthreads();

    for (int r = 0; r < UPB; ++r) {
        const int uidx = u0 + r;

        // ---- stage: group = wave; 32 rows x 128 fp32 -> bf16 LDS ----
        {
            const int g = wave;
            const float* table = (g < 2) ? emb : emb_var;
            const int side = g & 1;
            const int colf = (lane & 15) * 8;
            const int rsub = lane >> 4;
#pragma unroll
            for (int i = 0; i < 8; ++i) {
                int row = i * 4 + rsub;
                int sym = sidxL[r][2 * row + side];
                const float* src = table + (size_t)sym * DD + colf;
                float4 x0 = *(const float4*)src;
                float4 x1 = *(const float4*)(src + 4);
                *(bf16x8*)&Sg[(g * 32 + row) * PSTR + colf] = pack8(x0, x1);
            }
        }
        __syncthreads();

        // ---- MFMA: S[32x64 per wave] = cat * W^T ----
        const int pg = pw ? 2 : 0;
        f32x4 acc[2][4] = {};
#pragma unroll
        for (int kt = 0; kt < 8; ++kt) {
            const int g = (kt < 4) ? pg : pg + 1;
            const int coff = (kt & 3) * 32 + quad * 8;
            bf16x8 fa[2];
#pragma unroll
            for (int mt = 0; mt < 2; ++mt)
                fa[mt] = *(const bf16x8*)&Sg[(g * 32 + mt * 16 + m15) * PSTR + coff];
#pragma unroll
            for (int mt = 0; mt < 2; ++mt)
#pragma unroll
                for (int nt = 0; nt < 4; ++nt)
                    acc[mt][nt] = __builtin_amdgcn_mfma_f32_16x16x32_bf16(fa[mt], Bf[nt][kt], acc[mt][nt], 0, 0, 0);
        }

        // ---- epilogue: partial a[m] = sum_n u[n]*tanh(S+b) over this n-half ----
        {
            float part[2][4];
#pragma unroll
            for (int mt = 0; mt < 2; ++mt)
#pragma unroll
                for (int rr = 0; rr < 4; ++rr) {
                    float s = 0.f;
#pragma unroll
                    for (int nt = 0; nt < 4; ++nt)
                        s += un_[nt] * ftanh(acc[mt][nt][rr] + nb[nt]);
                    part[mt][rr] = s;
                }
#pragma unroll
            for (int off = 1; off < 16; off <<= 1)
#pragma unroll
                for (int mt = 0; mt < 2; ++mt)
#pragma unroll
                    for (int rr = 0; rr < 4; ++rr)
                        part[mt][rr] += __shfl_xor(part[mt][rr], off, 64);
            if (m15 == 0) {
#pragma unroll
                for (int mt = 0; mt < 2; ++mt)
#pragma unroll
                    for (int rr = 0; rr < 4; ++rr)
                        aP[pw][wn][mt * 16 + quad * 4 + rr] = part[mt][rr];
            }
        }
        __syncthreads();

        // ---- softmax over 30 neighbors: wave 0 -> p0, wave 2 -> p1 ----
        if ((wave & 1) == 0 && lane < 32) {
            const int p = wave >> 1;
            float sc = (lane < NBN) ? aP[p][0][lane] + aP[p][1][lane] : -1e30f;
            float mx = sc;
#pragma unroll
            for (int off = 1; off < 32; off <<= 1) mx = fmaxf(mx, __shfl_xor(mx, off, 64));
            float e = (lane < NBN) ? __expf(sc - mx) : 0.f;
            float sum = e;
#pragma unroll
            for (int off = 1; off < 32; off <<= 1) sum += __shfl_xor(sum, off, 64);
            attL[p][lane] = e / sum;
        }
        __syncthreads();

        // ---- pool ent_e (group 1, from emb — both paths) + tanh + store ----
        {
            const int p = tid >> 7;          // waves 0,1 -> p0; waves 2,3 -> p1
            const int d = tid & 127;
            float pool = 0.f;
#pragma unroll
            for (int k = 0; k < NBN; ++k)
                pool += attL[p][k] * bf2f(Sg[(32 + k) * PSTR + d]);
            if (uidx < TOTU) {
                float* dst;
                if (uidx < BQ)                 dst = query   + ((size_t)p * BQ + uidx) * TWOD;
                else if (uidx < 2 * BQ)        dst = query   + ((size_t)p * BQ + (uidx - BQ)) * TWOD + DD;
                else if (uidx < 2 * BQ + FEWN) dst = support + ((size_t)p * FEWN + (uidx - 2 * BQ)) * TWOD;
                else                           dst = support + ((size_t)p * FEWN + (uidx - 2 * BQ - FEWN)) * TWOD + DD;
                dst[d] = ftanh(pool);
            }
        }
        __syncthreads();   // protect Sg before next unit's staging
    }
}

// ---------------- K2: support encoder (MLP + residual + layernorm ddof=1) ------
template <int RPB>
__global__ __launch_bounds__(256) void k_supenc(
    const float* __restrict__ xin, float* __restrict__ xout,
    unsigned short* __restrict__ abf,
    const float* __restrict__ p1WT, const float* __restrict__ p1b,
    const float* __restrict__ p2WT, const float* __restrict__ p2b,
    const float* __restrict__ ln_a, const float* __restrict__ ln_b)
{
    const int tid = threadIdx.x;
    const int r0 = blockIdx.x * RPB;
    __shared__ float X[RPB][TWOD];
    __shared__ float H1[RPB][FOURD];
    __shared__ float red[4][RPB][2];
    __shared__ float muv[RPB], sgv[RPB];

    for (int idx = tid; idx < RPB * TWOD; idx += 256) {
        int r = idx >> 8, j = idx & 255;
        X[r][j] = xin[(size_t)(r0 + r) * TWOD + j];
    }
    __syncthreads();

    {
        float acc[RPB][2] = {};
        for (int j = 0; j < TWOD; j += 4) {
            float w0[4], w1[4];
#pragma unroll
            for (int jj = 0; jj < 4; ++jj) {
                w0[jj] = p1WT[(j + jj) * FOURD + tid];
                w1[jj] = p1WT[(j + jj) * FOURD + tid + 256];
            }
#pragma unroll
            for (int r = 0; r < RPB; ++r) {
                float x[4] __attribute__((aligned(16)));
                *(float4*)x = *(const float4*)&X[r][j];
#pragma unroll
                for (int jj = 0; jj < 4; ++jj) {
                    acc[r][0] += x[jj] * w0[jj];
                    acc[r][1] += x[jj] * w1[jj];
                }
            }
        }
        float b0 = p1b[tid], b1 = p1b[tid + 256];
#pragma unroll
        for (int r = 0; r < RPB; ++r) {
            H1[r][tid]       = fmaxf(acc[r][0] + b0, 0.f);
            H1[r][tid + 256] = fmaxf(acc[r][1] + b1, 0.f);
        }
    }
    __syncthreads();

    float z[RPB];
    {
        float acc[RPB] = {};
        for (int j = 0; j < FOURD; j += 4) {
            float w[4];
#pragma unroll
            for (int jj = 0; jj < 4; ++jj) w[jj] = p2WT[(j + jj) * TWOD + tid];
#pragma unroll
            for (int r = 0; r < RPB; ++r) {
                float h[4] __attribute__((aligned(16)));
                *(float4*)h = *(const float4*)&H1[r][j];
#pragma unroll
                for (int jj = 0; jj < 4; ++jj) acc[r] += h[jj] * w[jj];
            }
        }
        float b = p2b[tid];
#pragma unroll
        for (int r = 0; r < RPB; ++r) z[r] = acc[r] + b + X[r][tid];
    }
    {
        float s[RPB], ss[RPB];
#pragma unroll
        for (int r = 0; r < RPB; ++r) { s[r] = z[r]; ss[r] = z[r] * z[r]; }
#pragma unroll
        for (int off = 1; off < 64; off <<= 1)
#pragma unroll
            for (int r = 0; r < RPB; ++r) {
                s[r]  += __shfl_xor(s[r],  off, 64);
                ss[r] += __shfl_xor(ss[r], off, 64);
            }
        const int wv = tid >> 6, lane = tid & 63;
        if (lane == 0) {
#pragma unroll
            for (int r = 0; r < RPB; ++r) { red[wv][r][0] = s[r]; red[wv][r][1] = ss[r]; }
        }
        __syncthreads();
        if (tid < RPB) {
            float st  = red[0][tid][0] + red[1][tid][0] + red[2][tid][0] + red[3][tid][0];
            float sst = red[0][tid][1] + red[1][tid][1] + red[2][tid][1] + red[3][tid][1];
            float mu  = st / (float)TWOD;
            float var = fmaxf((sst - (float)TWOD * mu * mu) / ((float)TWOD - 1.f), 0.f);
            muv[tid] = mu; sgv[tid] = sqrtf(var);
        }
        __syncthreads();
    }
#pragma unroll
    for (int r = 0; r < RPB; ++r) {
        float o = (z[r] - muv[r]) / (sgv[r] + 1e-3f) * ln_a[tid] + ln_b[tid];
        xout[(size_t)(r0 + r) * TWOD + tid] = o;
        if (abf) abf[(size_t)(r0 + r) * KTOT + tid] = f2bf(o);
    }
}

// ---------------- K4a v2: LSTM gates, double-buffered prefetch GEMM ------------
// T3-minimal 2-phase pipeline: BK=64 (half the barriers of the old BK=32 loop),
// 2 LDS buffers; next tile's global_load_lds ISSUED before this tile's
// ds_read+MFMA so the ~300cy L2-hot load latency hides under compute, and only
// ONE barrier (with its vmcnt drain) per K-tile instead of two.
// nkt = count of 64-wide K tiles. Step 0: nkt=4 (K=256, h|r inputs are zero).
__global__ __launch_bounds__(256) void k_lstm_mfma(
    const unsigned short* __restrict__ Abf,
    const unsigned short* __restrict__ Wbf,
    const float* __restrict__ biasR,
    float* __restrict__ cst, float* __restrict__ hbuf,
    const int nkt)
{
    // [buf][khalf][128 rows x 32 cols bf16] = 8 KB each; total 64 KB
    __shared__ __align__(16) unsigned short As[2 * 2 * 4096];
    __shared__ __align__(16) unsigned short Bs[2 * 2 * 4096];
    const int tid  = threadIdx.x;
    const int wave = tid >> 6, lane = tid & 63;
    const int quad = lane >> 4, m15 = lane & 15;
    const int m0 = blockIdx.x * 128;
    const int n0 = blockIdx.y * 128;
    const int wm = wave >> 1, wn = wave & 1;
    const int lrow = lane >> 2, lslot = lane & 3;

    f32x4 acc[4][4] = {};

    auto stage = [&](int buf, int k0) {
#pragma unroll
        for (int t = 0; t < 2; ++t) {
            const int c = wave * 2 + t;
            const int row = c * 16 + lrow;
            const int kg = lslot ^ ((row >> 1) & 3);
#pragma unroll
            for (int kh = 0; kh < 2; ++kh) {
                gload_lds16(Abf + (size_t)(m0 + row) * KTOT + k0 + kh * 32 + kg * 8,
                            As + buf * 8192 + kh * 4096 + c * 512);
                gload_lds16(Wbf + (size_t)(n0 + row) * KTOT + k0 + kh * 32 + kg * 8,
                            Bs + buf * 8192 + kh * 4096 + c * 512);
            }
        }
    };

    auto compute = [&](int buf) {
#pragma unroll
        for (int kh = 0; kh < 2; ++kh) {
            const unsigned short* pA = As + buf * 8192 + kh * 4096;
            const unsigned short* pB = Bs + buf * 8192 + kh * 4096;
            bf16x8 fa[4], fb[4];
#pragma unroll
            for (int mi = 0; mi < 4; ++mi) {
                int ra = wm * 64 + mi * 16 + m15;
                int sa = quad ^ ((ra >> 1) & 3);
                fa[mi] = *(const bf16x8*)(pA + ra * 32 + sa * 8);
                int rb = wn * 64 + mi * 16 + m15;
                int sb = quad ^ ((rb >> 1) & 3);
                fb[mi] = *(const bf16x8*)(pB + rb * 32 + sb * 8);
            }
#pragma unroll
            for (int mi = 0; mi < 4; ++mi)
#pragma unroll
                for (int ni = 0; ni < 4; ++ni)
                    acc[mi][ni] = __builtin_amdgcn_mfma_f32_16x16x32_bf16(fa[mi], fb[ni], acc[mi][ni], 0, 0, 0);
        }
    };

    // prologue: fill buffer 0
    stage(0, 0);
    __syncthreads();                 // drains prologue staging

    int cur = 0;
    for (int kt = 0; kt < nkt; ++kt) {
        if (kt + 1 < nkt) stage(cur ^ 1, (kt + 1) * 64);   // issue-early (T14)
        compute(cur);                                      // hides load latency
        __syncthreads();             // one barrier/tile: reads done + prefetch drained
        cur ^= 1;
    }

    const int u = ((n0 + wn * 64) >> 2) + m15;
    float bg[4];
#pragma unroll
    for (int g = 0; g < 4; ++g) bg[g] = biasR[n0 + wn * 64 + g * 16 + m15];
#pragma unroll
    for (int mi = 0; mi < 4; ++mi) {
#pragma unroll
        for (int r = 0; r < 4; ++r) {
            int gm = m0 + wm * 64 + mi * 16 + quad * 4 + r;
            size_t cidx = (size_t)gm * ULIVE + u;
            float pi = acc[mi][0][r] + bg[0];
            float pf = acc[mi][1][r] + bg[1];
            float pg = acc[mi][2][r] + bg[2];
            float po = acc[mi][3][r] + bg[3];
            float cn = sigmoidf_(pf) * cst[cidx] + sigmoidf_(pi) * tanhf(pg);
            cst[cidx]  = cn;
            hbuf[cidx] = sigmoidf_(po) * tanhf(cn);
        }
    }
}

// ---------------- K4b: h, attention over support, write bf16 h|r ---------------
__global__ __launch_bounds__(256) void k_lstm_attn(
    const float* __restrict__ qg, const float* __restrict__ hbuf,
    const float* __restrict__ sg, unsigned short* __restrict__ Abf,
    float* __restrict__ hfin)
{
    const int tid = threadIdx.x;
    const int p   = blockIdx.y;
    const int wv = tid >> 6, lane = tid & 63;
    __shared__ float sgl[FEWN][TWOD];
    for (int idx = tid; idx < FEWN * TWOD; idx += 256)
        sgl[idx >> 8][idx & 255] = sg[p * FEWN * TWOD + idx];
    __syncthreads();
    const int j0 = lane * 4;
    for (int rr = 0; rr < 8; ++rr) {
        int row = blockIdx.x * 32 + wv * 8 + rr;
        size_t g = (size_t)p * BQ + row;
        float4 q4 = *(const float4*)(qg + g * TWOD + j0);
        float4 t4 = *(const float4*)(hbuf + g * ULIVE + j0);
        float h[4] __attribute__((aligned(16))) = {q4.x + t4.x, q4.y + t4.y, q4.z + t4.z, q4.w + t4.w};
        float sv[FEWN][4] __attribute__((aligned(16)));
        float pa[FEWN];
#pragma unroll
        for (int f = 0; f < FEWN; ++f) {
            *(float4*)sv[f] = *(const float4*)&sgl[f][j0];
            pa[f] = h[0] * sv[f][0] + h[1] * sv[f][1] + h[2] * sv[f][2] + h[3] * sv[f][3];
        }
#pragma unroll
        for (int off = 1; off < 64; off <<= 1)
#pragma unroll
            for (int f = 0; f < FEWN; ++f) pa[f] += __shfl_xor(pa[f], off, 64);
        float mx = pa[0];
#pragma unroll
        for (int f = 1; f < FEWN; ++f) mx = fmaxf(mx, pa[f]);
        float sum = 0.f, e[FEWN];
#pragma unroll
        for (int f = 0; f < FEWN; ++f) { e[f] = expf(pa[f] - mx); sum += e[f]; }
        float inv = 1.f / sum;
        float r4[4] __attribute__((aligned(16))) = {0.f, 0.f, 0.f, 0.f};
#pragma unroll
        for (int f = 0; f < FEWN; ++f) {
            float a = e[f] * inv;
#pragma unroll
            for (int q = 0; q < 4; ++q) r4[q] += a * sv[f][q];
        }
        unsigned short tb[4] __attribute__((aligned(8)));
#pragma unroll
        for (int q = 0; q < 4; ++q) tb[q] = f2bf(h[q]);
        *(uint2*)(Abf + g * KTOT + TWOD + j0) = *(uint2*)tb;
#pragma unroll
        for (int q = 0; q < 4; ++q) tb[q] = f2bf(r4[q]);
        *(uint2*)(Abf + g * KTOT + FOURD + j0) = *(uint2*)tb;
        *(float4*)(hfin + g * TWOD + j0) = *(float4*)h;
    }
}

// ---------------- K5: final scores ---------------------------------------------
__global__ __launch_bounds__(256) void k_score(
    const float* __restrict__ hfin, const float* __restrict__ sg, float* __restrict__ out)
{
    const int tid = threadIdx.x;
    const int p   = blockIdx.y;
    __shared__ float sm[TWOD];
    if (tid < TWOD) {
        const float* s = sg + p * FEWN * TWOD + tid;
        sm[tid] = (s[0] + s[TWOD] + s[2 * TWOD] + s[3 * TWOD] + s[4 * TWOD]) / 5.0f;
    }
    __syncthreads();
    const int wv = tid >> 6, lane = tid & 63;
    const int j0 = lane * 4;
    for (int rr = 0; rr < 8; ++rr) {
        int row = blockIdx.x * 32 + wv * 8 + rr;
        const float* h = hfin + ((size_t)p * BQ + row) * TWOD + j0;
        float4 h4 = *(const float4*)h;
        float4 s4 = *(const float4*)&sm[j0];
        float pv = h4.x * s4.x + h4.y * s4.y + h4.z * s4.z + h4.w * s4.w;
#pragma unroll
        for (int off = 1; off < 64; off <<= 1) pv += __shfl_xor(pv, off, 64);
        if (lane == 0) out[p * BQ + row] = pv;
    }
}

extern "C" void kernel_launch(void* const* d_in, const int* in_sizes, int n_in,
                              void* d_out, int out_size, void* d_ws, size_t ws_size,
                              hipStream_t stream)
{
    const float* emb     = (const float*)d_in[0];
    const float* emb_var = (const float*)d_in[1];
    const float* nW      = (const float*)d_in[2];
    const float* nWb     = (const float*)d_in[3];
    const float* nu      = (const float*)d_in[4];
    const float* nub     = (const float*)d_in[5];
    const float* nvW     = (const float*)d_in[6];
    const float* nvWb    = (const float*)d_in[7];
    const float* nvu     = (const float*)d_in[8];
    const float* nvub    = (const float*)d_in[9];
    const float* p1W     = (const float*)d_in[10];
    const float* p1b     = (const float*)d_in[11];
    const float* p2W     = (const float*)d_in[12];
    const float* p2b     = (const float*)d_in[13];
    const float* ln_a    = (const float*)d_in[14];
    const float* ln_b    = (const float*)d_in[15];
    const float* Wih     = (const float*)d_in[16];
    const float* Whh     = (const float*)d_in[17];
    const float* bih     = (const float*)d_in[18];
    const float* bhh     = (const float*)d_in[19];
    const int* q_left    = (const int*)d_in[20];
    const int* q_right   = (const int*)d_in[21];
    const int* s_left    = (const int*)d_in[22];
    const int* s_right   = (const int*)d_in[23];

    float* ws = (float*)d_ws;
    size_t o = 0;
    float* p1WT     = ws + o; o += FOURD * TWOD;
    float* p2WT     = ws + o; o += FOURD * TWOD;
    float* biasR    = ws + o; o += NGATE;
    float* query    = ws + o; o += (size_t)2 * BQ * TWOD;    // reused as hfin
    float* supportB = ws + o; o += 2 * FEWN * TWOD;
    float* qg       = ws + o; o += (size_t)2 * BQ * TWOD;
    float* sg       = ws + o; o += 2 * FEWN * TWOD;
    float* cst      = ws + o; o += (size_t)2 * BQ * ULIVE;
    float* hbuf     = ws + o; o += (size_t)2 * BQ * ULIVE;
    unsigned short* Wbf = (unsigned short*)(ws + o); o += (size_t)NGATE * KTOT / 2;
    unsigned short* Abf = (unsigned short*)(ws + o); o += (size_t)2 * BQ * KTOT / 2;
    unsigned short* Nbf = (unsigned short*)(ws + o); o += (size_t)2 * DD * TWOD / 2;
    float* hfin     = query;

    // cst must be zero for step 0 (f-gate multiplies it). Abf memset dropped:
    // step 0 runs K=256 (never reads h|r), and k_lstm_attn fully writes h|r
    // for every row before step 1 reads it.
    hipMemsetAsync(cst, 0, (size_t)2 * BQ * ULIVE * sizeof(float), stream);

    k_prep<<<dim3(1024), dim3(256), 0, stream>>>(Wih, Whh, bih, bhh, p1W, p2W, nW, nvW,
                                                 Wbf, biasR, p1WT, p2WT, Nbf);
    k_neighbor_v4<<<dim3((TOTU + UPB - 1) / UPB), dim3(256), 0, stream>>>(
        emb, emb_var, Nbf, nWb, nu, nvWb, nvu,
        q_left, q_right, s_left, s_right, query, supportB);
    k_supenc<8><<<dim3(2 * BQ / 8), dim3(256), 0, stream>>>(query, qg, Abf, p1WT, p1b, p2WT, p2b, ln_a, ln_b);
    k_supenc<1><<<dim3(2 * FEWN), dim3(256), 0, stream>>>(supportB, sg, (unsigned short*)nullptr,
                                                          p1WT, p1b, p2WT, p2b, ln_a, ln_b);
    for (int s = 0; s < 4; ++s) {
        k_lstm_mfma<<<dim3(2 * BQ / 128, NGATE / 128), dim3(256), 0, stream>>>(
            Abf, Wbf, biasR, cst, hbuf, s == 0 ? TWOD / 64 : KTOT / 64);
        k_lstm_attn<<<dim3(BQ / 32, 2), dim3(256), 0, stream>>>(qg, hbuf, sg, Abf, hfin);
    }
    k_score<<<dim3(BQ / 32, 2), dim3(256), 0, stream>>>(hfin, sg, (float*)d_out);
}

// Round 6
// 583.922 us; speedup vs baseline: 1.2794x; 1.0104x over previous
//
#include <hip/hip_runtime.h>
#include <math.h>

#define DD    128
#define TWOD  256
#define FOURD 512
#define NBN   30
#define BQ    4096
#define FEWN  5
#define NSYM  200000
#define KTOT  768    // 256 (query) + 256 (h) + 256 (r)
#define NGATE 1024   // 256 live units x 4 gates (units 256..511 are dead)
#define ULIVE 256
#define TOTU  (2 * BQ + 2 * FEWN)   // 8202 row-units
#define UPB   4                      // units per block (neighbor kernel)
#define PSTR  136                    // padded bf16 row stride (128 + 8)

typedef short bf16x8 __attribute__((ext_vector_type(8)));
typedef float f32x4 __attribute__((ext_vector_type(4)));

__device__ __forceinline__ float sigmoidf_(float x) { return 1.0f / (1.0f + expf(-x)); }

// fast tanh: 1 - 2/(e^{2x}+1)  (v_exp + v_rcp; |err| ~1e-6, saturates correctly)
__device__ __forceinline__ float ftanh(float x) {
    float e = __expf(2.0f * x);
    return 1.0f - 2.0f / (e + 1.0f);
}

__device__ __forceinline__ unsigned short f2bf(float f) {
    unsigned int u = __float_as_uint(f);
    unsigned int r = (u + 0x7fffu + ((u >> 16) & 1u)) >> 16;
    return (unsigned short)r;
}

__device__ __forceinline__ float bf2f(unsigned short s) {
    return __uint_as_float(((unsigned int)s) << 16);
}

// pack 8 fp32 -> bf16x8 (round-to-nearest-ish)
__device__ __forceinline__ bf16x8 pack8(float4 a, float4 b) {
    union { bf16x8 v; unsigned int u[4]; } r;
    r.u[0] = ((__float_as_uint(a.x) + 0x8000u) >> 16) | ((__float_as_uint(a.y) + 0x8000u) & 0xffff0000u);
    r.u[1] = ((__float_as_uint(a.z) + 0x8000u) >> 16) | ((__float_as_uint(a.w) + 0x8000u) & 0xffff0000u);
    r.u[2] = ((__float_as_uint(b.x) + 0x8000u) >> 16) | ((__float_as_uint(b.y) + 0x8000u) & 0xffff0000u);
    r.u[3] = ((__float_as_uint(b.z) + 0x8000u) >> 16) | ((__float_as_uint(b.w) + 0x8000u) & 0xffff0000u);
    return r.v;
}

__device__ __forceinline__ void gload_lds16(const void* g, void* l) {
    __builtin_amdgcn_global_load_lds((const __attribute__((address_space(1))) unsigned int*)g,
                                     (__attribute__((address_space(3))) unsigned int*)l,
                                     16, 0, 0);
}

// ---------------- K0: one-time weight prep -------------------------------------
__global__ __launch_bounds__(256) void k_prep(
    const float* __restrict__ Wih, const float* __restrict__ Whh,
    const float* __restrict__ bih, const float* __restrict__ bhh,
    const float* __restrict__ p1W, const float* __restrict__ p2W,
    const float* __restrict__ nW, const float* __restrict__ nvW,
    unsigned short* __restrict__ Wbf, float* __restrict__ biasR,
    float* __restrict__ p1WT, float* __restrict__ p2WT,
    unsigned short* __restrict__ Nbf)
{
    int idx = blockIdx.x * 256 + threadIdx.x;
    int stride = gridDim.x * 256;
    for (int i = idx; i < NGATE * KTOT; i += stride) {
        int n = i / KTOT, k = i - n * KTOT;
        int blk = n >> 6, rem = n & 63;
        int g = rem >> 4, ul = rem & 15;
        int u = blk * 16 + ul;
        int srcrow = g * 512 + u;
        float v = (k < TWOD) ? Wih[srcrow * TWOD + k] : Whh[srcrow * FOURD + (k - TWOD)];
        Wbf[i] = f2bf(v);
    }
    for (int n = idx; n < NGATE; n += stride) {
        int blk = n >> 6, rem = n & 63;
        int g = rem >> 4, ul = rem & 15;
        int u = blk * 16 + ul;
        int srcrow = g * 512 + u;
        biasR[n] = bih[srcrow] + bhh[srcrow];
    }
    for (int i = idx; i < FOURD * TWOD; i += stride) {
        int o = i / TWOD, j = i % TWOD;
        p1WT[j * FOURD + o] = p1W[o * TWOD + j];
    }
    for (int i = idx; i < TWOD * FOURD; i += stride) {
        int o = i / FOURD, j = i % FOURD;
        p2WT[j * TWOD + o] = p2W[o * FOURD + j];
    }
    for (int i = idx; i < 2 * DD * TWOD; i += stride) {
        float v = (i < DD * TWOD) ? nW[i] : nvW[i - DD * TWOD];
        Nbf[i] = f2bf(v);
    }
}

// ---------------- K1 v4: neighbor encoder, both paths, LDS-staged gather -------
// (Best measured variant: 154-156 us. v5-v8 restructurings all regressed.)
__global__ __launch_bounds__(256, 2) void k_neighbor_v4(
    const float* __restrict__ emb, const float* __restrict__ emb_var,
    const unsigned short* __restrict__ Nbf,
    const float* __restrict__ nWb, const float* __restrict__ nu,
    const float* __restrict__ nvWb, const float* __restrict__ nvu,
    const int* __restrict__ q_left, const int* __restrict__ q_right,
    const int* __restrict__ s_left, const int* __restrict__ s_right,
    float* __restrict__ query, float* __restrict__ support)
{
    const int tid  = threadIdx.x;
    const int wave = tid >> 6, lane = tid & 63;
    const int quad = lane >> 4, m15 = lane & 15;
    const int pw   = wave >> 1;          // path of this wave (MFMA phase)
    const int wn   = wave & 1;           // n-half
    const int u0   = blockIdx.x * UPB;

    __shared__ __align__(16) unsigned short Sg[4 * 32 * PSTR];  // 4 groups x 32 rows
    __shared__ int   sidxL[UPB][64];
    __shared__ float aP[2][2][32];
    __shared__ float attL[2][32];

    // ---- block init: neighbor indices for all UPB units ----
    {
        int un = tid >> 6, i = tid & 63;
        int uu_ = u0 + un; if (uu_ >= TOTU) uu_ = TOTU - 1;
        const int* conn;
        if (uu_ < BQ)                 conn = q_left  + uu_ * (NBN * 2);
        else if (uu_ < 2 * BQ)        conn = q_right + (uu_ - BQ) * (NBN * 2);
        else if (uu_ < 2 * BQ + FEWN) conn = s_left  + (uu_ - 2 * BQ) * (NBN * 2);
        else                          conn = s_right + (uu_ - 2 * BQ - FEWN) * (NBN * 2);
        sidxL[un][i] = (i < NBN * 2) ? conn[i] : NSYM;
    }

    // ---- per-wave constants: B fragments (128 VGPR), u & bias slices ----
    const unsigned short* Bw = Nbf + (size_t)pw * DD * TWOD;
    const float* Wb = pw ? nvWb : nWb;
    const float* uu = pw ? nvu  : nu;
    bf16x8 Bf[4][8];
    float nb[4], un_[4];
#pragma unroll
    for (int t = 0; t < 4; ++t) {
        int n = wn * 64 + t * 16 + m15;
#pragma unroll
        for (int kt = 0; kt < 8; ++kt)
            Bf[t][kt] = *(const bf16x8*)(Bw + n * TWOD + kt * 32 + quad * 8);
        nb[t] = Wb[n];
        un_[t] = uu[n];
    }
    __syncthreads();

    for (int r = 0; r < UPB; ++r) {
        const int uidx = u0 + r;

        // ---- stage: group = wave; 32 rows x 128 fp32 -> bf16 LDS ----
        {
            const int g = wave;
            const float* table = (g < 2) ? emb : emb_var;
            const int side = g & 1;
            const int colf = (lane & 15) * 8;
            const int rsub = lane >> 4;
#pragma unroll
            for (int i = 0; i < 8; ++i) {
                int row = i * 4 + rsub;
                int sym = sidxL[r][2 * row + side];
                const float* src = table + (size_t)sym * DD + colf;
                float4 x0 = *(const float4*)src;
                float4 x1 = *(const float4*)(src + 4);
                *(bf16x8*)&Sg[(g * 32 + row) * PSTR + colf] = pack8(x0, x1);
            }
        }
        __syncthreads();

        // ---- MFMA: S[32x64 per wave] = cat * W^T ----
        const int pg = pw ? 2 : 0;
        f32x4 acc[2][4] = {};
#pragma unroll
        for (int kt = 0; kt < 8; ++kt) {
            const int g = (kt < 4) ? pg : pg + 1;
            const int coff = (kt & 3) * 32 + quad * 8;
            bf16x8 fa[2];
#pragma unroll
            for (int mt = 0; mt < 2; ++mt)
                fa[mt] = *(const bf16x8*)&Sg[(g * 32 + mt * 16 + m15) * PSTR + coff];
#pragma unroll
            for (int mt = 0; mt < 2; ++mt)
#pragma unroll
                for (int nt = 0; nt < 4; ++nt)
                    acc[mt][nt] = __builtin_amdgcn_mfma_f32_16x16x32_bf16(fa[mt], Bf[nt][kt], acc[mt][nt], 0, 0, 0);
        }

        // ---- epilogue: partial a[m] = sum_n u[n]*tanh(S+b) over this n-half ----
        {
            float part[2][4];
#pragma unroll
            for (int mt = 0; mt < 2; ++mt)
#pragma unroll
                for (int rr = 0; rr < 4; ++rr) {
                    float s = 0.f;
#pragma unroll
                    for (int nt = 0; nt < 4; ++nt)
                        s += un_[nt] * ftanh(acc[mt][nt][rr] + nb[nt]);
                    part[mt][rr] = s;
                }
#pragma unroll
            for (int off = 1; off < 16; off <<= 1)
#pragma unroll
                for (int mt = 0; mt < 2; ++mt)
#pragma unroll
                    for (int rr = 0; rr < 4; ++rr)
                        part[mt][rr] += __shfl_xor(part[mt][rr], off, 64);
            if (m15 == 0) {
#pragma unroll
                for (int mt = 0; mt < 2; ++mt)
#pragma unroll
                    for (int rr = 0; rr < 4; ++rr)
                        aP[pw][wn][mt * 16 + quad * 4 + rr] = part[mt][rr];
            }
        }
        __syncthreads();

        // ---- softmax over 30 neighbors: wave 0 -> p0, wave 2 -> p1 ----
        if ((wave & 1) == 0 && lane < 32) {
            const int p = wave >> 1;
            float sc = (lane < NBN) ? aP[p][0][lane] + aP[p][1][lane] : -1e30f;
            float mx = sc;
#pragma unroll
            for (int off = 1; off < 32; off <<= 1) mx = fmaxf(mx, __shfl_xor(mx, off, 64));
            float e = (lane < NBN) ? __expf(sc - mx) : 0.f;
            float sum = e;
#pragma unroll
            for (int off = 1; off < 32; off <<= 1) sum += __shfl_xor(sum, off, 64);
            attL[p][lane] = e / sum;
        }
        __syncthreads();

        // ---- pool ent_e (group 1, from emb — both paths) + tanh + store ----
        {
            const int p = tid >> 7;          // waves 0,1 -> p0; waves 2,3 -> p1
            const int d = tid & 127;
            float pool = 0.f;
#pragma unroll
            for (int k = 0; k < NBN; ++k)
                pool += attL[p][k] * bf2f(Sg[(32 + k) * PSTR + d]);
            if (uidx < TOTU) {
                float* dst;
                if (uidx < BQ)                 dst = query   + ((size_t)p * BQ + uidx) * TWOD;
                else if (uidx < 2 * BQ)        dst = query   + ((size_t)p * BQ + (uidx - BQ)) * TWOD + DD;
                else if (uidx < 2 * BQ + FEWN) dst = support + ((size_t)p * FEWN + (uidx - 2 * BQ)) * TWOD;
                else                           dst = support + ((size_t)p * FEWN + (uidx - 2 * BQ - FEWN)) * TWOD + DD;
                dst[d] = ftanh(pool);
            }
        }
        __syncthreads();   // protect Sg before next unit's staging
    }
}

// ---------------- K2: support encoder (MLP + residual + layernorm ddof=1) ------
// xout may be nullptr (query path: the bf16 copy in Abf IS the downstream input).
template <int RPB>
__global__ __launch_bounds__(256) void k_supenc(
    const float* __restrict__ xin, float* __restrict__ xout,
    unsigned short* __restrict__ abf,
    const float* __restrict__ p1WT, const float* __restrict__ p1b,
    const float* __restrict__ p2WT, const float* __restrict__ p2b,
    const float* __restrict__ ln_a, const float* __restrict__ ln_b)
{
    const int tid = threadIdx.x;
    const int r0 = blockIdx.x * RPB;
    __shared__ float X[RPB][TWOD];
    __shared__ float H1[RPB][FOURD];
    __shared__ float red[4][RPB][2];
    __shared__ float muv[RPB], sgv[RPB];

    for (int idx = tid; idx < RPB * TWOD; idx += 256) {
        int r = idx >> 8, j = idx & 255;
        X[r][j] = xin[(size_t)(r0 + r) * TWOD + j];
    }
    __syncthreads();

    {
        float acc[RPB][2] = {};
        for (int j = 0; j < TWOD; j += 4) {
            float w0[4], w1[4];
#pragma unroll
            for (int jj = 0; jj < 4; ++jj) {
                w0[jj] = p1WT[(j + jj) * FOURD + tid];
                w1[jj] = p1WT[(j + jj) * FOURD + tid + 256];
            }
#pragma unroll
            for (int r = 0; r < RPB; ++r) {
                float x[4] __attribute__((aligned(16)));
                *(float4*)x = *(const float4*)&X[r][j];
#pragma unroll
                for (int jj = 0; jj < 4; ++jj) {
                    acc[r][0] += x[jj] * w0[jj];
                    acc[r][1] += x[jj] * w1[jj];
                }
            }
        }
        float b0 = p1b[tid], b1 = p1b[tid + 256];
#pragma unroll
        for (int r = 0; r < RPB; ++r) {
            H1[r][tid]       = fmaxf(acc[r][0] + b0, 0.f);
            H1[r][tid + 256] = fmaxf(acc[r][1] + b1, 0.f);
        }
    }
    __syncthreads();

    float z[RPB];
    {
        float acc[RPB] = {};
        for (int j = 0; j < FOURD; j += 4) {
            float w[4];
#pragma unroll
            for (int jj = 0; jj < 4; ++jj) w[jj] = p2WT[(j + jj) * TWOD + tid];
#pragma unroll
            for (int r = 0; r < RPB; ++r) {
                float h[4] __attribute__((aligned(16)));
                *(float4*)h = *(const float4*)&H1[r][j];
#pragma unroll
                for (int jj = 0; jj < 4; ++jj) acc[r] += h[jj] * w[jj];
            }
        }
        float b = p2b[tid];
#pragma unroll
        for (int r = 0; r < RPB; ++r) z[r] = acc[r] + b + X[r][tid];
    }
    {
        float s[RPB], ss[RPB];
#pragma unroll
        for (int r = 0; r < RPB; ++r) { s[r] = z[r]; ss[r] = z[r] * z[r]; }
#pragma unroll
        for (int off = 1; off < 64; off <<= 1)
#pragma unroll
            for (int r = 0; r < RPB; ++r) {
                s[r]  += __shfl_xor(s[r],  off, 64);
                ss[r] += __shfl_xor(ss[r], off, 64);
            }
        const int wv = tid >> 6, lane = tid & 63;
        if (lane == 0) {
#pragma unroll
            for (int r = 0; r < RPB; ++r) { red[wv][r][0] = s[r]; red[wv][r][1] = ss[r]; }
        }
        __syncthreads();
        if (tid < RPB) {
            float st  = red[0][tid][0] + red[1][tid][0] + red[2][tid][0] + red[3][tid][0];
            float sst = red[0][tid][1] + red[1][tid][1] + red[2][tid][1] + red[3][tid][1];
            float mu  = st / (float)TWOD;
            float var = fmaxf((sst - (float)TWOD * mu * mu) / ((float)TWOD - 1.f), 0.f);
            muv[tid] = mu; sgv[tid] = sqrtf(var);
        }
        __syncthreads();
    }
#pragma unroll
    for (int r = 0; r < RPB; ++r) {
        float o = (z[r] - muv[r]) / (sgv[r] + 1e-3f) * ln_a[tid] + ln_b[tid];
        if (xout) xout[(size_t)(r0 + r) * TWOD + tid] = o;
        if (abf)  abf[(size_t)(r0 + r) * KTOT + tid] = f2bf(o);
    }
}

// ---------------- K4a v2: LSTM gates, double-buffered prefetch GEMM ------------
// nkt = count of 64-wide K tiles. Step 0: nkt=4 (K=256, h|r inputs are zero).
// first: skip the cst load (c==0 at step 0 -> no memset needed).
// hbufB output is bf16 (h_r was rounded to bf16 downstream anyway).
__global__ __launch_bounds__(256) void k_lstm_mfma(
    const unsigned short* __restrict__ Abf,
    const unsigned short* __restrict__ Wbf,
    const float* __restrict__ biasR,
    float* __restrict__ cst, unsigned short* __restrict__ hbufB,
    const int nkt, const int first)
{
    // [buf][khalf][128 rows x 32 cols bf16] = 8 KB each; total 64 KB
    __shared__ __align__(16) unsigned short As[2 * 2 * 4096];
    __shared__ __align__(16) unsigned short Bs[2 * 2 * 4096];
    const int tid  = threadIdx.x;
    const int wave = tid >> 6, lane = tid & 63;
    const int quad = lane >> 4, m15 = lane & 15;
    const int m0 = blockIdx.x * 128;
    const int n0 = blockIdx.y * 128;
    const int wm = wave >> 1, wn = wave & 1;
    const int lrow = lane >> 2, lslot = lane & 3;

    f32x4 acc[4][4] = {};

    auto stage = [&](int buf, int k0) {
#pragma unroll
        for (int t = 0; t < 2; ++t) {
            const int c = wave * 2 + t;
            const int row = c * 16 + lrow;
            const int kg = lslot ^ ((row >> 1) & 3);
#pragma unroll
            for (int kh = 0; kh < 2; ++kh) {
                gload_lds16(Abf + (size_t)(m0 + row) * KTOT + k0 + kh * 32 + kg * 8,
                            As + buf * 8192 + kh * 4096 + c * 512);
                gload_lds16(Wbf + (size_t)(n0 + row) * KTOT + k0 + kh * 32 + kg * 8,
                            Bs + buf * 8192 + kh * 4096 + c * 512);
            }
        }
    };

    auto compute = [&](int buf) {
#pragma unroll
        for (int kh = 0; kh < 2; ++kh) {
            const unsigned short* pA = As + buf * 8192 + kh * 4096;
            const unsigned short* pB = Bs + buf * 8192 + kh * 4096;
            bf16x8 fa[4], fb[4];
#pragma unroll
            for (int mi = 0; mi < 4; ++mi) {
                int ra = wm * 64 + mi * 16 + m15;
                int sa = quad ^ ((ra >> 1) & 3);
                fa[mi] = *(const bf16x8*)(pA + ra * 32 + sa * 8);
                int rb = wn * 64 + mi * 16 + m15;
                int sb = quad ^ ((rb >> 1) & 3);
                fb[mi] = *(const bf16x8*)(pB + rb * 32 + sb * 8);
            }
#pragma unroll
            for (int mi = 0; mi < 4; ++mi)
#pragma unroll
                for (int ni = 0; ni < 4; ++ni)
                    acc[mi][ni] = __builtin_amdgcn_mfma_f32_16x16x32_bf16(fa[mi], fb[ni], acc[mi][ni], 0, 0, 0);
        }
    };

    // prologue: fill buffer 0
    stage(0, 0);
    __syncthreads();                 // drains prologue staging

    int cur = 0;
    for (int kt = 0; kt < nkt; ++kt) {
        if (kt + 1 < nkt) stage(cur ^ 1, (kt + 1) * 64);   // issue-early (T14)
        compute(cur);                                      // hides load latency
        __syncthreads();             // one barrier/tile: reads done + prefetch drained
        cur ^= 1;
    }

    const int u = ((n0 + wn * 64) >> 2) + m15;
    float bg[4];
#pragma unroll
    for (int g = 0; g < 4; ++g) bg[g] = biasR[n0 + wn * 64 + g * 16 + m15];
#pragma unroll
    for (int mi = 0; mi < 4; ++mi) {
#pragma unroll
        for (int r = 0; r < 4; ++r) {
            int gm = m0 + wm * 64 + mi * 16 + quad * 4 + r;
            size_t cidx = (size_t)gm * ULIVE + u;
            float pi = acc[mi][0][r] + bg[0];
            float pf = acc[mi][1][r] + bg[1];
            float pg = acc[mi][2][r] + bg[2];
            float po = acc[mi][3][r] + bg[3];
            float cprev = 0.f;
            if (!first) cprev = cst[cidx];
            float cn = sigmoidf_(pf) * cprev + sigmoidf_(pi) * tanhf(pg);
            cst[cidx]   = cn;
            hbufB[cidx] = f2bf(sigmoidf_(po) * tanhf(cn));
        }
    }
}

// ---------------- K4b v2: h, attention, write bf16 h|r; final step: scores -----
// q is read from Abf[:, :256] (the bf16 query_g supenc already wrote) — the f32
// qg buffer is gone. h_r comes from bf16 hbufB. On final_: skip the dead Abf
// h|r writes and emit score = h . mean(sg) directly (k_score fused away).
__global__ __launch_bounds__(256) void k_lstm_attn(
    const unsigned short* __restrict__ hbufB,
    const float* __restrict__ sg, unsigned short* __restrict__ Abf,
    float* __restrict__ out, const int final_)
{
    const int tid = threadIdx.x;
    const int p   = blockIdx.y;
    const int wv = tid >> 6, lane = tid & 63;
    __shared__ float sgl[FEWN][TWOD];
    __shared__ float sm[TWOD];
    for (int idx = tid; idx < FEWN * TWOD; idx += 256)
        sgl[idx >> 8][idx & 255] = sg[p * FEWN * TWOD + idx];
    __syncthreads();
    if (final_) {
        if (tid < TWOD)
            sm[tid] = (sgl[0][tid] + sgl[1][tid] + sgl[2][tid] + sgl[3][tid] + sgl[4][tid]) * 0.2f;
        __syncthreads();
    }
    const int j0 = lane * 4;
    for (int rr = 0; rr < 8; ++rr) {
        int row = blockIdx.x * 32 + wv * 8 + rr;
        size_t g = (size_t)p * BQ + row;
        union { uint2 v; unsigned short s[4]; } qq, tt;
        qq.v = *(const uint2*)(Abf + g * KTOT + j0);          // q (bf16)
        tt.v = *(const uint2*)(hbufB + g * ULIVE + j0);       // h_r (bf16)
        float h[4] __attribute__((aligned(16)));
#pragma unroll
        for (int q = 0; q < 4; ++q) h[q] = bf2f(qq.s[q]) + bf2f(tt.s[q]);
        float sv[FEWN][4] __attribute__((aligned(16)));
        float pa[FEWN];
#pragma unroll
        for (int f = 0; f < FEWN; ++f) {
            *(float4*)sv[f] = *(const float4*)&sgl[f][j0];
            pa[f] = h[0] * sv[f][0] + h[1] * sv[f][1] + h[2] * sv[f][2] + h[3] * sv[f][3];
        }
#pragma unroll
        for (int off = 1; off < 64; off <<= 1)
#pragma unroll
            for (int f = 0; f < FEWN; ++f) pa[f] += __shfl_xor(pa[f], off, 64);
        if (!final_) {
            float mx = pa[0];
#pragma unroll
            for (int f = 1; f < FEWN; ++f) mx = fmaxf(mx, pa[f]);
            float sum = 0.f, e[FEWN];
#pragma unroll
            for (int f = 0; f < FEWN; ++f) { e[f] = expf(pa[f] - mx); sum += e[f]; }
            float inv = 1.f / sum;
            float r4[4] __attribute__((aligned(16))) = {0.f, 0.f, 0.f, 0.f};
#pragma unroll
            for (int f = 0; f < FEWN; ++f) {
                float a = e[f] * inv;
#pragma unroll
                for (int q = 0; q < 4; ++q) r4[q] += a * sv[f][q];
            }
            unsigned short tb[4] __attribute__((aligned(8)));
#pragma unroll
            for (int q = 0; q < 4; ++q) tb[q] = f2bf(h[q]);
            *(uint2*)(Abf + g * KTOT + TWOD + j0) = *(uint2*)tb;
#pragma unroll
            for (int q = 0; q < 4; ++q) tb[q] = f2bf(r4[q]);
            *(uint2*)(Abf + g * KTOT + FOURD + j0) = *(uint2*)tb;
        } else {
            const float* s4 = &sm[j0];
            float pv = h[0] * s4[0] + h[1] * s4[1] + h[2] * s4[2] + h[3] * s4[3];
#pragma unroll
            for (int off = 1; off < 64; off <<= 1) pv += __shfl_xor(pv, off, 64);
            if (lane == 0) out[p * BQ + row] = pv;
        }
    }
}

extern "C" void kernel_launch(void* const* d_in, const int* in_sizes, int n_in,
                              void* d_out, int out_size, void* d_ws, size_t ws_size,
                              hipStream_t stream)
{
    const float* emb     = (const float*)d_in[0];
    const float* emb_var = (const float*)d_in[1];
    const float* nW      = (const float*)d_in[2];
    const float* nWb     = (const float*)d_in[3];
    const float* nu      = (const float*)d_in[4];
    const float* nub     = (const float*)d_in[5];
    const float* nvW     = (const float*)d_in[6];
    const float* nvWb    = (const float*)d_in[7];
    const float* nvu     = (const float*)d_in[8];
    const float* nvub    = (const float*)d_in[9];
    const float* p1W     = (const float*)d_in[10];
    const float* p1b     = (const float*)d_in[11];
    const float* p2W     = (const float*)d_in[12];
    const float* p2b     = (const float*)d_in[13];
    const float* ln_a    = (const float*)d_in[14];
    const float* ln_b    = (const float*)d_in[15];
    const float* Wih     = (const float*)d_in[16];
    const float* Whh     = (const float*)d_in[17];
    const float* bih     = (const float*)d_in[18];
    const float* bhh     = (const float*)d_in[19];
    const int* q_left    = (const int*)d_in[20];
    const int* q_right   = (const int*)d_in[21];
    const int* s_left    = (const int*)d_in[22];
    const int* s_right   = (const int*)d_in[23];

    float* ws = (float*)d_ws;
    size_t o = 0;
    float* p1WT     = ws + o; o += FOURD * TWOD;
    float* p2WT     = ws + o; o += FOURD * TWOD;
    float* biasR    = ws + o; o += NGATE;
    float* query    = ws + o; o += (size_t)2 * BQ * TWOD;
    float* supportB = ws + o; o += 2 * FEWN * TWOD;
    float* sg       = ws + o; o += 2 * FEWN * TWOD;
    float* cst      = ws + o; o += (size_t)2 * BQ * ULIVE;
    unsigned short* hbufB = (unsigned short*)(ws + o); o += (size_t)2 * BQ * ULIVE / 2;
    unsigned short* Wbf   = (unsigned short*)(ws + o); o += (size_t)NGATE * KTOT / 2;
    unsigned short* Abf   = (unsigned short*)(ws + o); o += (size_t)2 * BQ * KTOT / 2;
    unsigned short* Nbf   = (unsigned short*)(ws + o); o += (size_t)2 * DD * TWOD / 2;

    // No memsets: step 0 skips the cst read (first=1) and runs K=256 so the
    // h|r thirds of Abf are never read before k_lstm_attn writes them.

    k_prep<<<dim3(1024), dim3(256), 0, stream>>>(Wih, Whh, bih, bhh, p1W, p2W, nW, nvW,
                                                 Wbf, biasR, p1WT, p2WT, Nbf);
    k_neighbor_v4<<<dim3((TOTU + UPB - 1) / UPB), dim3(256), 0, stream>>>(
        emb, emb_var, Nbf, nWb, nu, nvWb, nvu,
        q_left, q_right, s_left, s_right, query, supportB);
    k_supenc<8><<<dim3(2 * BQ / 8), dim3(256), 0, stream>>>(query, (float*)nullptr, Abf,
                                                            p1WT, p1b, p2WT, p2b, ln_a, ln_b);
    k_supenc<1><<<dim3(2 * FEWN), dim3(256), 0, stream>>>(supportB, sg, (unsigned short*)nullptr,
                                                          p1WT, p1b, p2WT, p2b, ln_a, ln_b);
    for (int s = 0; s < 4; ++s) {
        k_lstm_mfma<<<dim3(2 * BQ / 128, NGATE / 128), dim3(256), 0, stream>>>(
            Abf, Wbf, biasR, cst, hbufB, s == 0 ? TWOD / 64 : KTOT / 64, s == 0 ? 1 : 0);
        k_lstm_attn<<<dim3(BQ / 32, 2), dim3(256), 0, stream>>>(
            hbufB, sg, Abf, (float*)d_out, s == 3 ? 1 : 0);
    }
}